// Round 8
// baseline (1474.333 us; speedup 1.0000x reference)
//
#include <hip/hip_runtime.h>
#include <hip/hip_bf16.h>

#define LEAKY 0.2f

// ---------------- CSR build ----------------

__global__ void k_zero_int(int* __restrict__ p, int n) {
    int i = blockIdx.x * blockDim.x + threadIdx.x;
    if (i < n) p[i] = 0;
}

__global__ void k_hist(const int* __restrict__ dst, int* __restrict__ cnt, int E, int N) {
    int e = blockIdx.x * blockDim.x + threadIdx.x;
    if (e >= E) return;
    int dn = dst[e];
    if ((unsigned)dn < (unsigned)N) atomicAdd(&cnt[dn], 1);
}

// single-block exclusive scan, shuffle-based (wave scan + cross-wave combine)
__global__ __launch_bounds__(1024)
void k_scan(const int* __restrict__ cnt, int* __restrict__ row_start,
            int* __restrict__ cursor, int N) {
    __shared__ int wsum[16];
    __shared__ int carry_s;
    const int tid  = threadIdx.x;
    const int wave = tid >> 6;
    const int lane = tid & 63;
    if (tid == 0) carry_s = 0;
    __syncthreads();
    for (int base = 0; base < N; base += 1024) {
        int i = base + tid;
        int v = (i < N) ? cnt[i] : 0;
        int x = v;
        #pragma unroll
        for (int off = 1; off < 64; off <<= 1) {
            int t = __shfl_up(x, off, 64);
            if (lane >= off) x += t;
        }
        if (lane == 63) wsum[wave] = x;
        __syncthreads();
        if (wave == 0 && lane < 16) {
            int y = wsum[lane];
            #pragma unroll
            for (int off = 1; off < 16; off <<= 1) {
                int t = __shfl_up(y, off, 64);
                if (lane >= off) y += t;
            }
            wsum[lane] = y;
        }
        __syncthreads();
        int carry = carry_s;
        int wbase = (wave > 0) ? wsum[wave - 1] : 0;
        int excl  = carry + wbase + x - v;
        if (i < N) { row_start[i] = excl; cursor[i] = excl; }
        int tot = wsum[15];
        __syncthreads();
        if (tid == 0) carry_s = carry + tot;
        __syncthreads();
    }
    if (tid == 0) row_start[N] = carry_s;
}

__global__ void k_scatter(const int* __restrict__ src, const int* __restrict__ dst,
                          int* __restrict__ cursor, int* __restrict__ src_sorted,
                          int E, int N) {
    int e = blockIdx.x * blockDim.x + threadIdx.x;
    if (e >= E) return;
    int dn = dst[e];
    if ((unsigned)dn >= (unsigned)N) return;
    int pos = atomicAdd(&cursor[dn], 1);
    src_sorted[pos] = src[e];
}

// ---------------- GEMM: double-buffered LDS, BM=128 x BN, BK=16 ----------------
// 256 threads; micro-tile 8 x (BN/16) per thread. One barrier per K-tile:
// prefetch tile k+1 into registers while computing tile k, store to the
// other LDS buffer, single __syncthreads().

template<int BN>
__global__ __launch_bounds__(256, 2)
void k_gemm_db(const float* __restrict__ A, const float* __restrict__ B,
               float* __restrict__ C, int N, int K, int M) {
    constexpr int JT = BN / 16;                 // cols per thread (8 or 4)
    constexpr int BPASS = (BN == 128) ? 2 : 1;  // B float4 loads per thread
    constexpr int BSTEP = (BN == 128) ? 8 : 16;
    __shared__ float As[2][16][132];
    __shared__ float Bs[2][16][BN + 4];
    const int tid = threadIdx.x;
    const int tx = tid & 15;
    const int ty = tid >> 4;
    const int row0 = blockIdx.y * 128;
    const int col0 = blockIdx.x * BN;

    const int arow = tid >> 2;            // 0..63 (+64 second pass)
    const int acol = (tid & 3) * 4;
    const int brow = (BN == 128) ? (tid >> 5) : (tid >> 4);
    const int bcol = (BN == 128) ? ((tid & 31) * 4) : ((tid & 15) * 4);

    float4 pa[2], pb[BPASS];

    auto loadTile = [&](int k0) {
        #pragma unroll
        for (int p = 0; p < 2; ++p) {
            int gr = row0 + arow + p * 64;
            pa[p] = make_float4(0.f, 0.f, 0.f, 0.f);
            if (gr < N) pa[p] = *(const float4*)(A + (size_t)gr * K + k0 + acol);
        }
        #pragma unroll
        for (int p = 0; p < BPASS; ++p)
            pb[p] = *(const float4*)(B + (size_t)(k0 + brow + p * BSTEP) * M + col0 + bcol);
    };
    auto storeLDS = [&](int buf) {
        #pragma unroll
        for (int p = 0; p < 2; ++p) {
            int r = arow + p * 64;
            As[buf][acol + 0][r] = pa[p].x;
            As[buf][acol + 1][r] = pa[p].y;
            As[buf][acol + 2][r] = pa[p].z;
            As[buf][acol + 3][r] = pa[p].w;
        }
        #pragma unroll
        for (int p = 0; p < BPASS; ++p) {
            int r = brow + p * BSTEP;
            Bs[buf][r][bcol + 0] = pb[p].x;
            Bs[buf][r][bcol + 1] = pb[p].y;
            Bs[buf][r][bcol + 2] = pb[p].z;
            Bs[buf][r][bcol + 3] = pb[p].w;
        }
    };

    float acc[8][JT] = {};

    loadTile(0);
    storeLDS(0);
    __syncthreads();
    int cur = 0;
    for (int k0 = 16; k0 <= K; k0 += 16) {
        const bool has_next = (k0 < K);
        if (has_next) loadTile(k0);
        #pragma unroll
        for (int kk = 0; kk < 16; ++kk) {
            float a[8], b[JT];
            #pragma unroll
            for (int i = 0; i < 8; ++i) a[i] = As[cur][kk][ty * 8 + i];
            #pragma unroll
            for (int j = 0; j < JT; ++j) b[j] = Bs[cur][kk][tx * JT + j];
            #pragma unroll
            for (int i = 0; i < 8; ++i)
                #pragma unroll
                for (int j = 0; j < JT; ++j)
                    acc[i][j] = fmaf(a[i], b[j], acc[i][j]);
        }
        if (has_next) {
            storeLDS(cur ^ 1);
            __syncthreads();
            cur ^= 1;
        }
    }

    #pragma unroll
    for (int i = 0; i < 8; ++i) {
        int r = row0 + ty * 8 + i;
        if (r < N) {
            #pragma unroll
            for (int q = 0; q < JT / 4; ++q) {
                *(float4*)(C + (size_t)r * M + col0 + tx * JT + q * 4) =
                    make_float4(acc[i][q * 4 + 0], acc[i][q * 4 + 1],
                                acc[i][q * 4 + 2], acc[i][q * 4 + 3]);
            }
        }
    }
}

// ---------------- attention pieces (CSR, atomic-free) ----------------

// one wave per (node,head): lane = d, coalesced feat read, shuffle reduce
__global__ __launch_bounds__(256)
void k_el_er(const float* __restrict__ feat, const float* __restrict__ al,
             const float* __restrict__ ar, float* __restrict__ el,
             float* __restrict__ er, int NH, int H) {
    int g = blockIdx.x * 4 + (threadIdx.x >> 6);
    int lane = threadIdx.x & 63;
    if (g >= NH) return;
    int h = g % H;
    float v  = feat[(size_t)g * 64 + lane];
    float sl = v * al[h * 64 + lane];
    float sr = v * ar[h * 64 + lane];
    #pragma unroll
    for (int off = 32; off; off >>= 1) {
        sl += __shfl_down(sl, off, 64);
        sr += __shfl_down(sr, off, 64);
    }
    if (lane == 0) { el[g] = sl; er[g] = sr; }
}

// per (node, head): online softmax max+sum over incoming edges, then a
// second pass writes the normalized weight per sorted edge: w[i*H+h].
__global__ void k_node_msw(const int* __restrict__ row_start, const int* __restrict__ src_sorted,
                           const float* __restrict__ el, const float* __restrict__ er,
                           float* __restrict__ w, int N, int H) {
    int idx = blockIdx.x * blockDim.x + threadIdx.x;
    if (idx >= N * H) return;
    int n = idx / H;
    int h = idx - n * H;
    float erv = er[idx];
    int b0 = row_start[n], b1 = row_start[n + 1];
    float mx = -INFINITY, sum = 0.f;
    for (int i = b0; i < b1; ++i) {
        float x = el[src_sorted[i] * H + h] + erv;
        x = (x > 0.f) ? x : LEAKY * x;
        if (x > mx) { sum = sum * __expf(mx - x) + 1.f; mx = x; }
        else        { sum += __expf(x - mx); }
    }
    float rs = 1.0f / fmaxf(sum, 1e-30f);
    for (int i = b0; i < b1; ++i) {
        float x = el[src_sorted[i] * H + h] + erv;
        x = (x > 0.f) ? x : LEAKY * x;
        w[(size_t)i * H + h] = __expf(x - mx) * rs;
    }
}

// Aggregation: 256 threads = (256/M) node-groups; each group of M threads
// owns one dst node, thread owns one (h,d) slot. 8-wide pipelined gather;
// weights precomputed per (edge,head) — wave-uniform loads.
__global__ __launch_bounds__(256)
void k_agg_csr(const int* __restrict__ row_start, const int* __restrict__ src_sorted,
               const float* __restrict__ feat, const float* __restrict__ w,
               const float* __restrict__ bias, float* __restrict__ out,
               int H, int N, int do_relu) {
    const int M = H * 64;
    const int G = 256 / M;
    const int grp = threadIdx.x / M;
    const int tid = threadIdx.x - grp * M;
    const int n = blockIdx.x * G + grp;
    if (n >= N) return;
    const int h = tid >> 6;

    float acc = bias[tid];
    int b0 = row_start[n], b1 = row_start[n + 1];
    int i = b0;
    for (; i + 8 <= b1; i += 8) {
        int ss[8]; float wv[8], fv[8];
        #pragma unroll
        for (int j = 0; j < 8; ++j) ss[j] = src_sorted[i + j];
        #pragma unroll
        for (int j = 0; j < 8; ++j) wv[j] = w[(size_t)(i + j) * H + h];
        #pragma unroll
        for (int j = 0; j < 8; ++j) fv[j] = feat[(size_t)ss[j] * M + tid];
        #pragma unroll
        for (int j = 0; j < 8; ++j) acc = fmaf(fv[j], wv[j], acc);
    }
    for (; i + 4 <= b1; i += 4) {
        int ss[4]; float wv[4], fv[4];
        #pragma unroll
        for (int j = 0; j < 4; ++j) ss[j] = src_sorted[i + j];
        #pragma unroll
        for (int j = 0; j < 4; ++j) wv[j] = w[(size_t)(i + j) * H + h];
        #pragma unroll
        for (int j = 0; j < 4; ++j) fv[j] = feat[(size_t)ss[j] * M + tid];
        #pragma unroll
        for (int j = 0; j < 4; ++j) acc = fmaf(fv[j], wv[j], acc);
    }
    for (; i < b1; ++i) {
        int sn = src_sorted[i];
        float wv = w[(size_t)i * H + h];
        acc = fmaf(feat[(size_t)sn * M + tid], wv, acc);
    }
    if (do_relu) acc = fmaxf(acc, 0.f);
    out[(size_t)n * M + tid] = acc;
}

// ---------------- host side ----------------

static void run_layer(const float* A, int K, const float* W,
                      const float* al_, const float* ar_, const float* b_, int H,
                      float* feat, float* rstOut,
                      float* el, float* er, float* w,
                      const int* row_start, const int* src_sorted,
                      int N, int E, bool do_relu, hipStream_t stream) {
    const int M = H * 64;
    if (M % 128 == 0) {
        dim3 gg(M / 128, (N + 127) / 128);
        k_gemm_db<128><<<gg, 256, 0, stream>>>(A, W, feat, N, K, M);
    } else {
        dim3 gg(M / 64, (N + 127) / 128);
        k_gemm_db<64><<<gg, 256, 0, stream>>>(A, W, feat, N, K, M);
    }

    int nh = N * H;
    k_el_er<<<(nh + 3) / 4, 256, 0, stream>>>(feat, al_, ar_, el, er, nh, H);
    k_node_msw<<<(nh + 255) / 256, 256, 0, stream>>>(row_start, src_sorted, el, er, w, N, H);

    int G = 256 / M;
    k_agg_csr<<<(N + G - 1) / G, 256, 0, stream>>>(row_start, src_sorted, feat, w,
                                                   b_, rstOut, H, N, do_relu ? 1 : 0);
}

extern "C" void kernel_launch(void* const* d_in, const int* in_sizes, int n_in,
                              void* d_out, int out_size, void* d_ws, size_t ws_size,
                              hipStream_t stream) {
    const float* features = (const float*)d_in[0];
    const int*   src = (const int*)d_in[1];
    const int*   dst = (const int*)d_in[2];
    const float* W1  = (const float*)d_in[3];
    const float* al1 = (const float*)d_in[4];
    const float* ar1 = (const float*)d_in[5];
    const float* b1  = (const float*)d_in[6];
    const float* W2  = (const float*)d_in[7];
    const float* al2 = (const float*)d_in[8];
    const float* ar2 = (const float*)d_in[9];
    const float* b2  = (const float*)d_in[10];
    const float* W3  = (const float*)d_in[11];
    const float* al3 = (const float*)d_in[12];
    const float* ar3 = (const float*)d_in[13];
    const float* b3  = (const float*)d_in[14];

    const int N = in_sizes[0] / 128;   // 50000
    const int E = in_sizes[1];         // 800000

    float* ws   = (float*)d_ws;
    size_t n256 = (size_t)N * 256;
    float* bufA = ws;                        // [N,256]
    float* bufB = bufA + n256;               // [N,256]
    float* el   = bufB + n256;               // [N,4]
    float* er   = el + (size_t)N * 4;        // [N,4]
    float* w    = er + (size_t)N * 4;        // [E,4]
    int* cnt        = (int*)(w + (size_t)E * 4);   // [N]
    int* row_start  = cnt + N;                      // [N+1]
    int* cursor     = row_start + N + 1;            // [N]
    int* src_sorted = cursor + N;                   // [E]

    // ---- build dst-CSR (every call; deterministic, graph-capture safe) ----
    k_zero_int<<<(N + 255) / 256, 256, 0, stream>>>(cnt, N);
    k_hist<<<(E + 255) / 256, 256, 0, stream>>>(dst, cnt, E, N);
    k_scan<<<1, 1024, 0, stream>>>(cnt, row_start, cursor, N);
    k_scatter<<<(E + 255) / 256, 256, 0, stream>>>(src, dst, cursor, src_sorted, E, N);

    // layer 1: A=features[N,128] -> feat=bufB[N,256] -> rst=bufA[N,256] (+relu)
    run_layer(features, 128, W1, al1, ar1, b1, 4, bufB, bufA,
              el, er, w, row_start, src_sorted, N, E, true, stream);
    // layer 2
    run_layer(bufA, 256, W2, al2, ar2, b2, 4, bufB, bufA,
              el, er, w, row_start, src_sorted, N, E, true, stream);
    // layer 3: H=1; mean over 1 head is identity -> write straight to d_out
    run_layer(bufA, 256, W3, al3, ar3, b3, 1, bufB, (float*)d_out,
              el, er, w, row_start, src_sorted, N, E, false, stream);
}

// Round 9
// 736.688 us; speedup vs baseline: 2.0013x; 2.0013x over previous
//
#include <hip/hip_runtime.h>
#include <hip/hip_bf16.h>

#define LEAKY 0.2f

typedef __attribute__((ext_vector_type(8))) short short8;
typedef __attribute__((ext_vector_type(4))) float f32x4;

// round-to-nearest-even float -> bf16 bits (finite inputs)
__device__ inline unsigned short f2b(float f) {
    unsigned u = __float_as_uint(f);
    u += 0x7FFFu + ((u >> 16) & 1u);
    return (unsigned short)(u >> 16);
}

// ---------------- CSR build ----------------

__global__ void k_zero_int(int* __restrict__ p, int n) {
    int i = blockIdx.x * blockDim.x + threadIdx.x;
    if (i < n) p[i] = 0;
}

__global__ void k_hist(const int* __restrict__ dst, int* __restrict__ cnt, int E, int N) {
    int e = blockIdx.x * blockDim.x + threadIdx.x;
    if (e >= E) return;
    int dn = dst[e];
    if ((unsigned)dn < (unsigned)N) atomicAdd(&cnt[dn], 1);
}

__global__ __launch_bounds__(1024)
void k_scan(const int* __restrict__ cnt, int* __restrict__ row_start,
            int* __restrict__ cursor, int N) {
    __shared__ int wsum[16];
    __shared__ int carry_s;
    const int tid  = threadIdx.x;
    const int wave = tid >> 6;
    const int lane = tid & 63;
    if (tid == 0) carry_s = 0;
    __syncthreads();
    for (int base = 0; base < N; base += 1024) {
        int i = base + tid;
        int v = (i < N) ? cnt[i] : 0;
        int x = v;
        #pragma unroll
        for (int off = 1; off < 64; off <<= 1) {
            int t = __shfl_up(x, off, 64);
            if (lane >= off) x += t;
        }
        if (lane == 63) wsum[wave] = x;
        __syncthreads();
        if (wave == 0 && lane < 16) {
            int y = wsum[lane];
            #pragma unroll
            for (int off = 1; off < 16; off <<= 1) {
                int t = __shfl_up(y, off, 64);
                if (lane >= off) y += t;
            }
            wsum[lane] = y;
        }
        __syncthreads();
        int carry = carry_s;
        int wbase = (wave > 0) ? wsum[wave - 1] : 0;
        int excl  = carry + wbase + x - v;
        if (i < N) { row_start[i] = excl; cursor[i] = excl; }
        int tot = wsum[15];
        __syncthreads();
        if (tid == 0) carry_s = carry + tot;
        __syncthreads();
    }
    if (tid == 0) row_start[N] = carry_s;
}

__global__ void k_scatter(const int* __restrict__ src, const int* __restrict__ dst,
                          int* __restrict__ cursor, int* __restrict__ src_sorted,
                          int E, int N) {
    int e = blockIdx.x * blockDim.x + threadIdx.x;
    if (e >= E) return;
    int dn = dst[e];
    if ((unsigned)dn >= (unsigned)N) return;
    int pos = atomicAdd(&cursor[dn], 1);
    src_sorted[pos] = src[e];
}

// ---------------- weight pre-transpose to bf16: Wt[m][k] = bf16(W[k][m]) ----

__global__ void k_wt(const float* __restrict__ W, unsigned short* __restrict__ Wt,
                     int K, int M) {
    int idx = blockIdx.x * blockDim.x + threadIdx.x;
    if (idx >= K * M) return;
    int mcol = idx / K;
    int k = idx - mcol * K;
    Wt[idx] = f2b(W[(size_t)k * M + mcol]);
}

// ---------------- MFMA GEMM: C[N,M] = A[N,K]*W[K,M], bf16 in / fp32 acc ----
// 128x128 block tile, 256 threads = 4 waves (2x2), each wave 64x64 =
// 4x4 mfma_f32_16x16x32_bf16 tiles. A converted fp32->bf16 during staging.
// LDS rows padded to 40 bf16 (80 B) -> 2-way bank aliasing only (free).

__global__ __launch_bounds__(256)
void k_gemm_mfma(const float* __restrict__ A, const unsigned short* __restrict__ Wt,
                 float* __restrict__ C, int N, int K, int M) {
    constexpr int STR = 40;
    __shared__ unsigned short As[128 * STR];
    __shared__ unsigned short Bs[128 * STR];
    const int tid  = threadIdx.x;
    const int wave = tid >> 6;
    const int lane = tid & 63;
    const int row0 = blockIdx.y * 128;
    const int col0 = blockIdx.x * 128;
    const int wr = (wave >> 1) * 64;
    const int wc = (wave & 1) * 64;
    const int m16 = lane & 15;
    const int q   = lane >> 4;

    const int s_row = tid >> 2;          // 0..63 (+64 second pass)
    const int s_chk = (tid & 3) * 8;     // k offset 0,8,16,24
    const int b_row = tid >> 1;          // 0..127
    const int b_off = (tid & 1) * 16;    // k offset 0 or 16

    f32x4 acc[4][4] = {};

    for (int k0 = 0; k0 < K; k0 += 32) {
        // stage A: 128 rows x 32 k, fp32 -> bf16
        #pragma unroll
        for (int p = 0; p < 2; ++p) {
            int r = s_row + p * 64;
            int gr = row0 + r;
            float4 v0 = make_float4(0.f, 0.f, 0.f, 0.f);
            float4 v1 = make_float4(0.f, 0.f, 0.f, 0.f);
            if (gr < N) {
                const float* ap = A + (size_t)gr * K + k0 + s_chk;
                v0 = *(const float4*)ap;
                v1 = *(const float4*)(ap + 4);
            }
            short8 pk;
            pk[0] = (short)f2b(v0.x); pk[1] = (short)f2b(v0.y);
            pk[2] = (short)f2b(v0.z); pk[3] = (short)f2b(v0.w);
            pk[4] = (short)f2b(v1.x); pk[5] = (short)f2b(v1.y);
            pk[6] = (short)f2b(v1.z); pk[7] = (short)f2b(v1.w);
            *(short8*)&As[r * STR + s_chk] = pk;
        }
        // stage Bt: 128 cols x 32 k (already bf16)
        {
            const unsigned short* sp = Wt + (size_t)(col0 + b_row) * K + k0 + b_off;
            *(short8*)&Bs[b_row * STR + b_off]     = *(const short8*)sp;
            *(short8*)&Bs[b_row * STR + b_off + 8] = *(const short8*)(sp + 8);
        }
        __syncthreads();

        short8 afr[4], bfr[4];
        #pragma unroll
        for (int rg = 0; rg < 4; ++rg)
            afr[rg] = *(const short8*)&As[(wr + rg * 16 + m16) * STR + q * 8];
        #pragma unroll
        for (int cg = 0; cg < 4; ++cg)
            bfr[cg] = *(const short8*)&Bs[(wc + cg * 16 + m16) * STR + q * 8];
        #pragma unroll
        for (int rg = 0; rg < 4; ++rg)
            #pragma unroll
            for (int cg = 0; cg < 4; ++cg)
                acc[rg][cg] = __builtin_amdgcn_mfma_f32_16x16x32_bf16(
                    afr[rg], bfr[cg], acc[rg][cg], 0, 0, 0);
        __syncthreads();
    }

    // epilogue: D[row=q*4+r][col=m16]
    #pragma unroll
    for (int rg = 0; rg < 4; ++rg) {
        #pragma unroll
        for (int r = 0; r < 4; ++r) {
            int gr = row0 + wr + rg * 16 + q * 4 + r;
            if (gr < N) {
                float* cp = C + (size_t)gr * M + col0 + wc + m16;
                #pragma unroll
                for (int cg = 0; cg < 4; ++cg)
                    cp[cg * 16] = acc[rg][cg][r];
            }
        }
    }
}

// ---------------- fp32 GEMM (layer 3, M=64): single-buffered, proven ----

__global__ __launch_bounds__(256)
void k_gemm64(const float* __restrict__ A, const float* __restrict__ B,
              float* __restrict__ C, int N, int K, int M) {
    __shared__ float As[16][132];
    __shared__ float Bs[16][68];
    const int tid = threadIdx.x;
    const int tx = tid & 15;
    const int ty = tid >> 4;
    const int row0 = blockIdx.y * 128;
    const int col0 = blockIdx.x * 64;

    const int arow = tid >> 2;
    const int acol = (tid & 3) * 4;
    const int brow = tid >> 4;
    const int bcol = (tid & 15) * 4;

    float acc[8][4] = {};

    for (int k0 = 0; k0 < K; k0 += 16) {
        #pragma unroll
        for (int p = 0; p < 2; ++p) {
            int r = arow + p * 64;
            int gr = row0 + r;
            float4 av = make_float4(0.f, 0.f, 0.f, 0.f);
            if (gr < N) av = *(const float4*)(A + (size_t)gr * K + k0 + acol);
            As[acol + 0][r] = av.x;
            As[acol + 1][r] = av.y;
            As[acol + 2][r] = av.z;
            As[acol + 3][r] = av.w;
        }
        {
            float4 bv = *(const float4*)(B + (size_t)(k0 + brow) * M + col0 + bcol);
            Bs[brow][bcol + 0] = bv.x;
            Bs[brow][bcol + 1] = bv.y;
            Bs[brow][bcol + 2] = bv.z;
            Bs[brow][bcol + 3] = bv.w;
        }
        __syncthreads();

        #pragma unroll
        for (int kk = 0; kk < 16; ++kk) {
            float a[8], b[4];
            #pragma unroll
            for (int i = 0; i < 8; ++i) a[i] = As[kk][ty * 8 + i];
            #pragma unroll
            for (int j = 0; j < 4; ++j) b[j] = Bs[kk][tx * 4 + j];
            #pragma unroll
            for (int i = 0; i < 8; ++i)
                #pragma unroll
                for (int j = 0; j < 4; ++j)
                    acc[i][j] = fmaf(a[i], b[j], acc[i][j]);
        }
        __syncthreads();
    }

    #pragma unroll
    for (int i = 0; i < 8; ++i) {
        int r = row0 + ty * 8 + i;
        if (r < N) {
            float4 o = make_float4(acc[i][0], acc[i][1], acc[i][2], acc[i][3]);
            *(float4*)(C + (size_t)r * M + col0 + tx * 4) = o;
        }
    }
}

// ---------------- attention pieces (CSR, atomic-free) ----------------

__global__ __launch_bounds__(256)
void k_el_er(const float* __restrict__ feat, const float* __restrict__ al,
             const float* __restrict__ ar, float* __restrict__ el,
             float* __restrict__ er, int NH, int H) {
    int g = blockIdx.x * 4 + (threadIdx.x >> 6);
    int lane = threadIdx.x & 63;
    if (g >= NH) return;
    int h = g % H;
    float v  = feat[(size_t)g * 64 + lane];
    float sl = v * al[h * 64 + lane];
    float sr = v * ar[h * 64 + lane];
    #pragma unroll
    for (int off = 32; off; off >>= 1) {
        sl += __shfl_down(sl, off, 64);
        sr += __shfl_down(sr, off, 64);
    }
    if (lane == 0) { el[g] = sl; er[g] = sr; }
}

// per (node, head): online softmax, then write normalized w per sorted edge
__global__ void k_node_msw(const int* __restrict__ row_start, const int* __restrict__ src_sorted,
                           const float* __restrict__ el, const float* __restrict__ er,
                           float* __restrict__ w, int N, int H) {
    int idx = blockIdx.x * blockDim.x + threadIdx.x;
    if (idx >= N * H) return;
    int n = idx / H;
    int h = idx - n * H;
    float erv = er[idx];
    int b0 = row_start[n], b1 = row_start[n + 1];
    float mx = -INFINITY, sum = 0.f;
    for (int i = b0; i < b1; ++i) {
        float x = el[src_sorted[i] * H + h] + erv;
        x = (x > 0.f) ? x : LEAKY * x;
        if (x > mx) { sum = sum * __expf(mx - x) + 1.f; mx = x; }
        else        { sum += __expf(x - mx); }
    }
    float rs = 1.0f / fmaxf(sum, 1e-30f);
    for (int i = b0; i < b1; ++i) {
        float x = el[src_sorted[i] * H + h] + erv;
        x = (x > 0.f) ? x : LEAKY * x;
        w[(size_t)i * H + h] = __expf(x - mx) * rs;
    }
}

// Aggregation: 8-wide pipelined gather, precomputed per-(edge,head) weights
__global__ __launch_bounds__(256)
void k_agg_csr(const int* __restrict__ row_start, const int* __restrict__ src_sorted,
               const float* __restrict__ feat, const float* __restrict__ w,
               const float* __restrict__ bias, float* __restrict__ out,
               int H, int N, int do_relu) {
    const int M = H * 64;
    const int G = 256 / M;
    const int grp = threadIdx.x / M;
    const int tid = threadIdx.x - grp * M;
    const int n = blockIdx.x * G + grp;
    if (n >= N) return;
    const int h = tid >> 6;

    float acc = bias[tid];
    int b0 = row_start[n], b1 = row_start[n + 1];
    int i = b0;
    for (; i + 8 <= b1; i += 8) {
        int ss[8]; float wv[8], fv[8];
        #pragma unroll
        for (int j = 0; j < 8; ++j) ss[j] = src_sorted[i + j];
        #pragma unroll
        for (int j = 0; j < 8; ++j) wv[j] = w[(size_t)(i + j) * H + h];
        #pragma unroll
        for (int j = 0; j < 8; ++j) fv[j] = feat[(size_t)ss[j] * M + tid];
        #pragma unroll
        for (int j = 0; j < 8; ++j) acc = fmaf(fv[j], wv[j], acc);
    }
    for (; i + 4 <= b1; i += 4) {
        int ss[4]; float wv[4], fv[4];
        #pragma unroll
        for (int j = 0; j < 4; ++j) ss[j] = src_sorted[i + j];
        #pragma unroll
        for (int j = 0; j < 4; ++j) wv[j] = w[(size_t)(i + j) * H + h];
        #pragma unroll
        for (int j = 0; j < 4; ++j) fv[j] = feat[(size_t)ss[j] * M + tid];
        #pragma unroll
        for (int j = 0; j < 4; ++j) acc = fmaf(fv[j], wv[j], acc);
    }
    for (; i < b1; ++i) {
        int sn = src_sorted[i];
        float wv = w[(size_t)i * H + h];
        acc = fmaf(feat[(size_t)sn * M + tid], wv, acc);
    }
    if (do_relu) acc = fmaxf(acc, 0.f);
    out[(size_t)n * M + tid] = acc;
}

// ---------------- host side ----------------

static void run_layer(const float* A, int K, const float* W, unsigned short* Wt,
                      const float* al_, const float* ar_, const float* b_, int H,
                      float* feat, float* rstOut,
                      float* el, float* er, float* w,
                      const int* row_start, const int* src_sorted,
                      int N, int E, bool do_relu, hipStream_t stream) {
    const int M = H * 64;
    if (M % 128 == 0) {
        // bf16 MFMA path: pre-transpose W to Wt[m][k] bf16, then MFMA GEMM
        k_wt<<<(K * M + 255) / 256, 256, 0, stream>>>(W, Wt, K, M);
        dim3 gg(M / 128, (N + 127) / 128);
        k_gemm_mfma<<<gg, 256, 0, stream>>>(A, Wt, feat, N, K, M);
    } else {
        dim3 gg(M / 64, (N + 127) / 128);
        k_gemm64<<<gg, 256, 0, stream>>>(A, W, feat, N, K, M);
    }

    int nh = N * H;
    k_el_er<<<(nh + 3) / 4, 256, 0, stream>>>(feat, al_, ar_, el, er, nh, H);
    k_node_msw<<<(nh + 255) / 256, 256, 0, stream>>>(row_start, src_sorted, el, er, w, N, H);

    int G = 256 / M;
    k_agg_csr<<<(N + G - 1) / G, 256, 0, stream>>>(row_start, src_sorted, feat, w,
                                                   b_, rstOut, H, N, do_relu ? 1 : 0);
}

extern "C" void kernel_launch(void* const* d_in, const int* in_sizes, int n_in,
                              void* d_out, int out_size, void* d_ws, size_t ws_size,
                              hipStream_t stream) {
    const float* features = (const float*)d_in[0];
    const int*   src = (const int*)d_in[1];
    const int*   dst = (const int*)d_in[2];
    const float* W1  = (const float*)d_in[3];
    const float* al1 = (const float*)d_in[4];
    const float* ar1 = (const float*)d_in[5];
    const float* b1  = (const float*)d_in[6];
    const float* W2  = (const float*)d_in[7];
    const float* al2 = (const float*)d_in[8];
    const float* ar2 = (const float*)d_in[9];
    const float* b2  = (const float*)d_in[10];
    const float* W3  = (const float*)d_in[11];
    const float* al3 = (const float*)d_in[12];
    const float* ar3 = (const float*)d_in[13];
    const float* b3  = (const float*)d_in[14];

    const int N = in_sizes[0] / 128;   // 50000
    const int E = in_sizes[1];         // 800000

    float* ws   = (float*)d_ws;
    size_t n256 = (size_t)N * 256;
    float* bufA = ws;                        // [N,256]
    float* bufB = bufA + n256;               // [N,256]
    float* el   = bufB + n256;               // [N,4]
    float* er   = el + (size_t)N * 4;        // [N,4]
    float* w    = er + (size_t)N * 4;        // [E,4]
    int* cnt        = (int*)(w + (size_t)E * 4);   // [N]
    int* row_start  = cnt + N;                      // [N+1]
    int* cursor     = row_start + N + 1;            // [N]
    int* src_sorted = cursor + N;                   // [E]
    uintptr_t wp = (uintptr_t)(src_sorted + E);
    wp = (wp + 15) & ~(uintptr_t)15;
    unsigned short* Wt = (unsigned short*)wp;       // [256*256] bf16 max

    // ---- build dst-CSR (every call; deterministic, graph-capture safe) ----
    k_zero_int<<<(N + 255) / 256, 256, 0, stream>>>(cnt, N);
    k_hist<<<(E + 255) / 256, 256, 0, stream>>>(dst, cnt, E, N);
    k_scan<<<1, 1024, 0, stream>>>(cnt, row_start, cursor, N);
    k_scatter<<<(E + 255) / 256, 256, 0, stream>>>(src, dst, cursor, src_sorted, E, N);

    // layer 1: A=features[N,128] -> feat=bufB[N,256] -> rst=bufA[N,256] (+relu)
    run_layer(features, 128, W1, Wt, al1, ar1, b1, 4, bufB, bufA,
              el, er, w, row_start, src_sorted, N, E, true, stream);
    // layer 2
    run_layer(bufA, 256, W2, Wt, al2, ar2, b2, 4, bufB, bufA,
              el, er, w, row_start, src_sorted, N, E, true, stream);
    // layer 3: H=1, fp32 exact; mean over 1 head is identity -> d_out
    run_layer(bufA, 256, W3, Wt, al3, ar3, b3, 1, bufB, (float*)d_out,
              el, er, w, row_start, src_sorted, N, E, false, stream);
}

// Round 10
// 720.937 us; speedup vs baseline: 2.0450x; 1.0218x over previous
//
#include <hip/hip_runtime.h>
#include <hip/hip_bf16.h>

#define LEAKY 0.2f

typedef __attribute__((ext_vector_type(8))) short short8;
typedef __attribute__((ext_vector_type(4))) float f32x4;

// round-to-nearest-even float -> bf16 bits (finite inputs)
__device__ inline unsigned short f2b(float f) {
    unsigned u = __float_as_uint(f);
    u += 0x7FFFu + ((u >> 16) & 1u);
    return (unsigned short)(u >> 16);
}
__device__ inline float b2f(unsigned short s) {
    return __uint_as_float(((unsigned)s) << 16);
}

// ---------------- CSR build ----------------

__global__ void k_zero_int(int* __restrict__ p, int n) {
    int i = blockIdx.x * blockDim.x + threadIdx.x;
    if (i < n) p[i] = 0;
}

__global__ void k_hist(const int* __restrict__ dst, int* __restrict__ cnt, int E, int N) {
    int e = blockIdx.x * blockDim.x + threadIdx.x;
    if (e >= E) return;
    int dn = dst[e];
    if ((unsigned)dn < (unsigned)N) atomicAdd(&cnt[dn], 1);
}

__global__ __launch_bounds__(1024)
void k_scan(const int* __restrict__ cnt, int* __restrict__ row_start,
            int* __restrict__ cursor, int N) {
    __shared__ int wsum[16];
    __shared__ int carry_s;
    const int tid  = threadIdx.x;
    const int wave = tid >> 6;
    const int lane = tid & 63;
    if (tid == 0) carry_s = 0;
    __syncthreads();
    for (int base = 0; base < N; base += 1024) {
        int i = base + tid;
        int v = (i < N) ? cnt[i] : 0;
        int x = v;
        #pragma unroll
        for (int off = 1; off < 64; off <<= 1) {
            int t = __shfl_up(x, off, 64);
            if (lane >= off) x += t;
        }
        if (lane == 63) wsum[wave] = x;
        __syncthreads();
        if (wave == 0 && lane < 16) {
            int y = wsum[lane];
            #pragma unroll
            for (int off = 1; off < 16; off <<= 1) {
                int t = __shfl_up(y, off, 64);
                if (lane >= off) y += t;
            }
            wsum[lane] = y;
        }
        __syncthreads();
        int carry = carry_s;
        int wbase = (wave > 0) ? wsum[wave - 1] : 0;
        int excl  = carry + wbase + x - v;
        if (i < N) { row_start[i] = excl; cursor[i] = excl; }
        int tot = wsum[15];
        __syncthreads();
        if (tid == 0) carry_s = carry + tot;
        __syncthreads();
    }
    if (tid == 0) row_start[N] = carry_s;
}

__global__ void k_scatter(const int* __restrict__ src, const int* __restrict__ dst,
                          int* __restrict__ cursor, int* __restrict__ src_sorted,
                          int E, int N) {
    int e = blockIdx.x * blockDim.x + threadIdx.x;
    if (e >= E) return;
    int dn = dst[e];
    if ((unsigned)dn >= (unsigned)N) return;
    int pos = atomicAdd(&cursor[dn], 1);
    src_sorted[pos] = src[e];
}

// ---------------- weight pre-transpose to bf16: Wt[m][k] = bf16(W[k][m]) ----

__global__ void k_wt(const float* __restrict__ W, unsigned short* __restrict__ Wt,
                     int K, int M) {
    int idx = blockIdx.x * blockDim.x + threadIdx.x;
    if (idx >= K * M) return;
    int mcol = idx / K;
    int k = idx - mcol * K;
    Wt[idx] = f2b(W[(size_t)k * M + mcol]);
}

// ---------------- MFMA GEMM: C[N,M] = A[N,K]*W[K,M], bf16 in / fp32 acc ----
// 128x128 block tile, 256 threads = 4 waves (2x2), each wave 64x64.
// Emits fp32 C (softmax path) AND bf16 shadow Cb (aggregation gather).

__global__ __launch_bounds__(256)
void k_gemm_mfma(const float* __restrict__ A, const unsigned short* __restrict__ Wt,
                 float* __restrict__ C, unsigned short* __restrict__ Cb,
                 int N, int K, int M) {
    constexpr int STR = 40;
    __shared__ unsigned short As[128 * STR];
    __shared__ unsigned short Bs[128 * STR];
    const int tid  = threadIdx.x;
    const int wave = tid >> 6;
    const int lane = tid & 63;
    const int row0 = blockIdx.y * 128;
    const int col0 = blockIdx.x * 128;
    const int wr = (wave >> 1) * 64;
    const int wc = (wave & 1) * 64;
    const int m16 = lane & 15;
    const int q   = lane >> 4;

    const int s_row = tid >> 2;
    const int s_chk = (tid & 3) * 8;
    const int b_row = tid >> 1;
    const int b_off = (tid & 1) * 16;

    f32x4 acc[4][4] = {};

    for (int k0 = 0; k0 < K; k0 += 32) {
        #pragma unroll
        for (int p = 0; p < 2; ++p) {
            int r = s_row + p * 64;
            int gr = row0 + r;
            float4 v0 = make_float4(0.f, 0.f, 0.f, 0.f);
            float4 v1 = make_float4(0.f, 0.f, 0.f, 0.f);
            if (gr < N) {
                const float* ap = A + (size_t)gr * K + k0 + s_chk;
                v0 = *(const float4*)ap;
                v1 = *(const float4*)(ap + 4);
            }
            short8 pk;
            pk[0] = (short)f2b(v0.x); pk[1] = (short)f2b(v0.y);
            pk[2] = (short)f2b(v0.z); pk[3] = (short)f2b(v0.w);
            pk[4] = (short)f2b(v1.x); pk[5] = (short)f2b(v1.y);
            pk[6] = (short)f2b(v1.z); pk[7] = (short)f2b(v1.w);
            *(short8*)&As[r * STR + s_chk] = pk;
        }
        {
            const unsigned short* sp = Wt + (size_t)(col0 + b_row) * K + k0 + b_off;
            *(short8*)&Bs[b_row * STR + b_off]     = *(const short8*)sp;
            *(short8*)&Bs[b_row * STR + b_off + 8] = *(const short8*)(sp + 8);
        }
        __syncthreads();

        short8 afr[4], bfr[4];
        #pragma unroll
        for (int rg = 0; rg < 4; ++rg)
            afr[rg] = *(const short8*)&As[(wr + rg * 16 + m16) * STR + q * 8];
        #pragma unroll
        for (int cg = 0; cg < 4; ++cg)
            bfr[cg] = *(const short8*)&Bs[(wc + cg * 16 + m16) * STR + q * 8];
        #pragma unroll
        for (int rg = 0; rg < 4; ++rg)
            #pragma unroll
            for (int cg = 0; cg < 4; ++cg)
                acc[rg][cg] = __builtin_amdgcn_mfma_f32_16x16x32_bf16(
                    afr[rg], bfr[cg], acc[rg][cg], 0, 0, 0);
        __syncthreads();
    }

    // epilogue: D[row=q*4+r][col=m16]; write fp32 + bf16 shadow
    #pragma unroll
    for (int rg = 0; rg < 4; ++rg) {
        #pragma unroll
        for (int r = 0; r < 4; ++r) {
            int gr = row0 + wr + rg * 16 + q * 4 + r;
            if (gr < N) {
                float*          cp = C  + (size_t)gr * M + col0 + wc + m16;
                unsigned short* bp = Cb + (size_t)gr * M + col0 + wc + m16;
                #pragma unroll
                for (int cg = 0; cg < 4; ++cg) {
                    float v = acc[rg][cg][r];
                    cp[cg * 16] = v;
                    bp[cg * 16] = f2b(v);
                }
            }
        }
    }
}

// ---------------- fp32 GEMM (layer 3, M=64): single-buffered, proven ----

__global__ __launch_bounds__(256)
void k_gemm64(const float* __restrict__ A, const float* __restrict__ B,
              float* __restrict__ C, int N, int K, int M) {
    __shared__ float As[16][132];
    __shared__ float Bs[16][68];
    const int tid = threadIdx.x;
    const int tx = tid & 15;
    const int ty = tid >> 4;
    const int row0 = blockIdx.y * 128;
    const int col0 = blockIdx.x * 64;

    const int arow = tid >> 2;
    const int acol = (tid & 3) * 4;
    const int brow = tid >> 4;
    const int bcol = (tid & 15) * 4;

    float acc[8][4] = {};

    for (int k0 = 0; k0 < K; k0 += 16) {
        #pragma unroll
        for (int p = 0; p < 2; ++p) {
            int r = arow + p * 64;
            int gr = row0 + r;
            float4 av = make_float4(0.f, 0.f, 0.f, 0.f);
            if (gr < N) av = *(const float4*)(A + (size_t)gr * K + k0 + acol);
            As[acol + 0][r] = av.x;
            As[acol + 1][r] = av.y;
            As[acol + 2][r] = av.z;
            As[acol + 3][r] = av.w;
        }
        {
            float4 bv = *(const float4*)(B + (size_t)(k0 + brow) * M + col0 + bcol);
            Bs[brow][bcol + 0] = bv.x;
            Bs[brow][bcol + 1] = bv.y;
            Bs[brow][bcol + 2] = bv.z;
            Bs[brow][bcol + 3] = bv.w;
        }
        __syncthreads();

        #pragma unroll
        for (int kk = 0; kk < 16; ++kk) {
            float a[8], b[4];
            #pragma unroll
            for (int i = 0; i < 8; ++i) a[i] = As[kk][ty * 8 + i];
            #pragma unroll
            for (int j = 0; j < 4; ++j) b[j] = Bs[kk][tx * 4 + j];
            #pragma unroll
            for (int i = 0; i < 8; ++i)
                #pragma unroll
                for (int j = 0; j < 4; ++j)
                    acc[i][j] = fmaf(a[i], b[j], acc[i][j]);
        }
        __syncthreads();
    }

    #pragma unroll
    for (int i = 0; i < 8; ++i) {
        int r = row0 + ty * 8 + i;
        if (r < N) {
            float4 o = make_float4(acc[i][0], acc[i][1], acc[i][2], acc[i][3]);
            *(float4*)(C + (size_t)r * M + col0 + tx * 4) = o;
        }
    }
}

// ---------------- attention pieces (CSR, atomic-free) ----------------

__global__ __launch_bounds__(256)
void k_el_er(const float* __restrict__ feat, const float* __restrict__ al,
             const float* __restrict__ ar, float* __restrict__ el,
             float* __restrict__ er, int NH, int H) {
    int g = blockIdx.x * 4 + (threadIdx.x >> 6);
    int lane = threadIdx.x & 63;
    if (g >= NH) return;
    int h = g % H;
    float v  = feat[(size_t)g * 64 + lane];
    float sl = v * al[h * 64 + lane];
    float sr = v * ar[h * 64 + lane];
    #pragma unroll
    for (int off = 32; off; off >>= 1) {
        sl += __shfl_down(sl, off, 64);
        sr += __shfl_down(sr, off, 64);
    }
    if (lane == 0) { el[g] = sl; er[g] = sr; }
}

// per (node, head): online softmax, then write normalized w per sorted edge
__global__ void k_node_msw(const int* __restrict__ row_start, const int* __restrict__ src_sorted,
                           const float* __restrict__ el, const float* __restrict__ er,
                           float* __restrict__ w, int N, int H) {
    int idx = blockIdx.x * blockDim.x + threadIdx.x;
    if (idx >= N * H) return;
    int n = idx / H;
    int h = idx - n * H;
    float erv = er[idx];
    int b0 = row_start[n], b1 = row_start[n + 1];
    float mx = -INFINITY, sum = 0.f;
    for (int i = b0; i < b1; ++i) {
        float x = el[src_sorted[i] * H + h] + erv;
        x = (x > 0.f) ? x : LEAKY * x;
        if (x > mx) { sum = sum * __expf(mx - x) + 1.f; mx = x; }
        else        { sum += __expf(x - mx); }
    }
    float rs = 1.0f / fmaxf(sum, 1e-30f);
    for (int i = b0; i < b1; ++i) {
        float x = el[src_sorted[i] * H + h] + erv;
        x = (x > 0.f) ? x : LEAKY * x;
        w[(size_t)i * H + h] = __expf(x - mx) * rs;
    }
}

// Aggregation: 8-wide pipelined gather; BF16 templated feat dtype.
template<int BF>
__global__ __launch_bounds__(256)
void k_agg_csr(const int* __restrict__ row_start, const int* __restrict__ src_sorted,
               const void* __restrict__ featv, const float* __restrict__ w,
               const float* __restrict__ bias, float* __restrict__ out,
               int H, int N, int do_relu) {
    const int M = H * 64;
    const int G = 256 / M;
    const int grp = threadIdx.x / M;
    const int tid = threadIdx.x - grp * M;
    const int n = blockIdx.x * G + grp;
    if (n >= N) return;
    const int h = tid >> 6;
    const float* ff = (const float*)featv;
    const unsigned short* fb = (const unsigned short*)featv;

    float acc = bias[tid];
    int b0 = row_start[n], b1 = row_start[n + 1];
    int i = b0;
    for (; i + 8 <= b1; i += 8) {
        int ss[8]; float wv[8], fv[8];
        #pragma unroll
        for (int j = 0; j < 8; ++j) ss[j] = src_sorted[i + j];
        #pragma unroll
        for (int j = 0; j < 8; ++j) wv[j] = w[(size_t)(i + j) * H + h];
        #pragma unroll
        for (int j = 0; j < 8; ++j)
            fv[j] = BF ? b2f(fb[(size_t)ss[j] * M + tid]) : ff[(size_t)ss[j] * M + tid];
        #pragma unroll
        for (int j = 0; j < 8; ++j) acc = fmaf(fv[j], wv[j], acc);
    }
    for (; i + 4 <= b1; i += 4) {
        int ss[4]; float wv[4], fv[4];
        #pragma unroll
        for (int j = 0; j < 4; ++j) ss[j] = src_sorted[i + j];
        #pragma unroll
        for (int j = 0; j < 4; ++j) wv[j] = w[(size_t)(i + j) * H + h];
        #pragma unroll
        for (int j = 0; j < 4; ++j)
            fv[j] = BF ? b2f(fb[(size_t)ss[j] * M + tid]) : ff[(size_t)ss[j] * M + tid];
        #pragma unroll
        for (int j = 0; j < 4; ++j) acc = fmaf(fv[j], wv[j], acc);
    }
    for (; i < b1; ++i) {
        int sn = src_sorted[i];
        float wv = w[(size_t)i * H + h];
        float fv = BF ? b2f(fb[(size_t)sn * M + tid]) : ff[(size_t)sn * M + tid];
        acc = fmaf(fv, wv, acc);
    }
    if (do_relu) acc = fmaxf(acc, 0.f);
    out[(size_t)n * M + tid] = acc;
}

// ---------------- host side ----------------

static void run_layer(const float* A, int K, const float* W, unsigned short* Wt,
                      const float* al_, const float* ar_, const float* b_, int H,
                      float* feat, unsigned short* featb, float* rstOut,
                      float* el, float* er, float* w,
                      const int* row_start, const int* src_sorted,
                      int N, int E, bool do_relu, hipStream_t stream) {
    const int M = H * 64;
    const bool mfma = (M % 128 == 0);
    if (mfma) {
        k_wt<<<(K * M + 255) / 256, 256, 0, stream>>>(W, Wt, K, M);
        dim3 gg(M / 128, (N + 127) / 128);
        k_gemm_mfma<<<gg, 256, 0, stream>>>(A, Wt, feat, featb, N, K, M);
    } else {
        dim3 gg(M / 64, (N + 127) / 128);
        k_gemm64<<<gg, 256, 0, stream>>>(A, W, feat, N, K, M);
    }

    int nh = N * H;
    k_el_er<<<(nh + 3) / 4, 256, 0, stream>>>(feat, al_, ar_, el, er, nh, H);
    k_node_msw<<<(nh + 255) / 256, 256, 0, stream>>>(row_start, src_sorted, el, er, w, N, H);

    int G = 256 / M;
    if (mfma) {
        k_agg_csr<1><<<(N + G - 1) / G, 256, 0, stream>>>(row_start, src_sorted, featb, w,
                                                          b_, rstOut, H, N, do_relu ? 1 : 0);
    } else {
        k_agg_csr<0><<<(N + G - 1) / G, 256, 0, stream>>>(row_start, src_sorted, feat, w,
                                                          b_, rstOut, H, N, do_relu ? 1 : 0);
    }
}

extern "C" void kernel_launch(void* const* d_in, const int* in_sizes, int n_in,
                              void* d_out, int out_size, void* d_ws, size_t ws_size,
                              hipStream_t stream) {
    const float* features = (const float*)d_in[0];
    const int*   src = (const int*)d_in[1];
    const int*   dst = (const int*)d_in[2];
    const float* W1  = (const float*)d_in[3];
    const float* al1 = (const float*)d_in[4];
    const float* ar1 = (const float*)d_in[5];
    const float* b1  = (const float*)d_in[6];
    const float* W2  = (const float*)d_in[7];
    const float* al2 = (const float*)d_in[8];
    const float* ar2 = (const float*)d_in[9];
    const float* b2  = (const float*)d_in[10];
    const float* W3  = (const float*)d_in[11];
    const float* al3 = (const float*)d_in[12];
    const float* ar3 = (const float*)d_in[13];
    const float* b3  = (const float*)d_in[14];

    const int N = in_sizes[0] / 128;   // 50000
    const int E = in_sizes[1];         // 800000

    float* ws   = (float*)d_ws;
    size_t n256 = (size_t)N * 256;
    float* bufA = ws;                        // [N,256]
    float* bufB = bufA + n256;               // [N,256]
    float* el   = bufB + n256;               // [N,4]
    float* er   = el + (size_t)N * 4;        // [N,4]
    float* w    = er + (size_t)N * 4;        // [E,4]
    int* cnt        = (int*)(w + (size_t)E * 4);   // [N]
    int* row_start  = cnt + N;                      // [N+1]
    int* cursor     = row_start + N + 1;            // [N]
    int* src_sorted = cursor + N;                   // [E]
    uintptr_t wp = (uintptr_t)(src_sorted + E);
    wp = (wp + 15) & ~(uintptr_t)15;
    unsigned short* Wt = (unsigned short*)wp;       // [256*256] bf16 max
    unsigned short* featb = Wt + 256 * 256;         // [N,256] bf16 shadow of feat

    // ---- build dst-CSR (every call; deterministic, graph-capture safe) ----
    k_zero_int<<<(N + 255) / 256, 256, 0, stream>>>(cnt, N);
    k_hist<<<(E + 255) / 256, 256, 0, stream>>>(dst, cnt, E, N);
    k_scan<<<1, 1024, 0, stream>>>(cnt, row_start, cursor, N);
    k_scatter<<<(E + 255) / 256, 256, 0, stream>>>(src, dst, cursor, src_sorted, E, N);

    // layer 1: A=features[N,128] -> feat=bufB[N,256] -> rst=bufA[N,256] (+relu)
    run_layer(features, 128, W1, Wt, al1, ar1, b1, 4, bufB, featb, bufA,
              el, er, w, row_start, src_sorted, N, E, true, stream);
    // layer 2
    run_layer(bufA, 256, W2, Wt, al2, ar2, b2, 4, bufB, featb, bufA,
              el, er, w, row_start, src_sorted, N, E, true, stream);
    // layer 3: H=1, fp32 exact; mean over 1 head is identity -> d_out
    run_layer(bufA, 256, W3, Wt, al3, ar3, b3, 1, bufB, featb, (float*)d_out,
              el, er, w, row_start, src_sorted, N, E, false, stream);
}

// Round 11
// 650.134 us; speedup vs baseline: 2.2677x; 1.1089x over previous
//
#include <hip/hip_runtime.h>
#include <hip/hip_bf16.h>

#define LEAKY 0.2f

typedef __attribute__((ext_vector_type(8))) short short8;
typedef __attribute__((ext_vector_type(4))) float f32x4;

// round-to-nearest-even float -> bf16 bits (finite inputs)
__device__ inline unsigned short f2b(float f) {
    unsigned u = __float_as_uint(f);
    u += 0x7FFFu + ((u >> 16) & 1u);
    return (unsigned short)(u >> 16);
}

// ---------------- CSR build ----------------

__global__ void k_zero_int(int* __restrict__ p, int n) {
    int i = blockIdx.x * blockDim.x + threadIdx.x;
    if (i < n) p[i] = 0;
}

__global__ void k_hist(const int* __restrict__ dst, int* __restrict__ cnt, int E, int N) {
    int e = blockIdx.x * blockDim.x + threadIdx.x;
    if (e >= E) return;
    int dn = dst[e];
    if ((unsigned)dn < (unsigned)N) atomicAdd(&cnt[dn], 1);
}

__global__ __launch_bounds__(1024)
void k_scan(const int* __restrict__ cnt, int* __restrict__ row_start,
            int* __restrict__ cursor, int N) {
    __shared__ int wsum[16];
    __shared__ int carry_s;
    const int tid  = threadIdx.x;
    const int wave = tid >> 6;
    const int lane = tid & 63;
    if (tid == 0) carry_s = 0;
    __syncthreads();
    for (int base = 0; base < N; base += 1024) {
        int i = base + tid;
        int v = (i < N) ? cnt[i] : 0;
        int x = v;
        #pragma unroll
        for (int off = 1; off < 64; off <<= 1) {
            int t = __shfl_up(x, off, 64);
            if (lane >= off) x += t;
        }
        if (lane == 63) wsum[wave] = x;
        __syncthreads();
        if (wave == 0 && lane < 16) {
            int y = wsum[lane];
            #pragma unroll
            for (int off = 1; off < 16; off <<= 1) {
                int t = __shfl_up(y, off, 64);
                if (lane >= off) y += t;
            }
            wsum[lane] = y;
        }
        __syncthreads();
        int carry = carry_s;
        int wbase = (wave > 0) ? wsum[wave - 1] : 0;
        int excl  = carry + wbase + x - v;
        if (i < N) { row_start[i] = excl; cursor[i] = excl; }
        int tot = wsum[15];
        __syncthreads();
        if (tid == 0) carry_s = carry + tot;
        __syncthreads();
    }
    if (tid == 0) row_start[N] = carry_s;
}

__global__ void k_scatter(const int* __restrict__ src, const int* __restrict__ dst,
                          int* __restrict__ cursor, int* __restrict__ src_sorted,
                          int E, int N) {
    int e = blockIdx.x * blockDim.x + threadIdx.x;
    if (e >= E) return;
    int dn = dst[e];
    if ((unsigned)dn >= (unsigned)N) return;
    int pos = atomicAdd(&cursor[dn], 1);
    src_sorted[pos] = src[e];
}

// ---------------- weight pre-transpose to bf16: Wt[m][k] = bf16(W[k][m]) ----

__global__ void k_wt(const float* __restrict__ W, unsigned short* __restrict__ Wt,
                     int K, int M) {
    int idx = blockIdx.x * blockDim.x + threadIdx.x;
    if (idx >= K * M) return;
    int mcol = idx / K;
    int k = idx - mcol * K;
    Wt[idx] = f2b(W[(size_t)k * M + mcol]);
}

// ---------------- MFMA GEMM (BN=128): C[N,M]=A[N,K]*W[K,M], bf16 in/fp32 acc
// 128x128 block tile, 4 waves (2x2), each wave 64x64. Emits fp32 C + bf16 Cb.

__global__ __launch_bounds__(256)
void k_gemm_mfma(const float* __restrict__ A, const unsigned short* __restrict__ Wt,
                 float* __restrict__ C, unsigned short* __restrict__ Cb,
                 int N, int K, int M) {
    constexpr int STR = 40;
    __shared__ unsigned short As[128 * STR];
    __shared__ unsigned short Bs[128 * STR];
    const int tid  = threadIdx.x;
    const int wave = tid >> 6;
    const int lane = tid & 63;
    const int row0 = blockIdx.y * 128;
    const int col0 = blockIdx.x * 128;
    const int wr = (wave >> 1) * 64;
    const int wc = (wave & 1) * 64;
    const int m16 = lane & 15;
    const int q   = lane >> 4;

    const int s_row = tid >> 2;
    const int s_chk = (tid & 3) * 8;
    const int b_row = tid >> 1;
    const int b_off = (tid & 1) * 16;

    f32x4 acc[4][4] = {};

    for (int k0 = 0; k0 < K; k0 += 32) {
        #pragma unroll
        for (int p = 0; p < 2; ++p) {
            int r = s_row + p * 64;
            int gr = row0 + r;
            float4 v0 = make_float4(0.f, 0.f, 0.f, 0.f);
            float4 v1 = make_float4(0.f, 0.f, 0.f, 0.f);
            if (gr < N) {
                const float* ap = A + (size_t)gr * K + k0 + s_chk;
                v0 = *(const float4*)ap;
                v1 = *(const float4*)(ap + 4);
            }
            short8 pk;
            pk[0] = (short)f2b(v0.x); pk[1] = (short)f2b(v0.y);
            pk[2] = (short)f2b(v0.z); pk[3] = (short)f2b(v0.w);
            pk[4] = (short)f2b(v1.x); pk[5] = (short)f2b(v1.y);
            pk[6] = (short)f2b(v1.z); pk[7] = (short)f2b(v1.w);
            *(short8*)&As[r * STR + s_chk] = pk;
        }
        {
            const unsigned short* sp = Wt + (size_t)(col0 + b_row) * K + k0 + b_off;
            *(short8*)&Bs[b_row * STR + b_off]     = *(const short8*)sp;
            *(short8*)&Bs[b_row * STR + b_off + 8] = *(const short8*)(sp + 8);
        }
        __syncthreads();

        short8 afr[4], bfr[4];
        #pragma unroll
        for (int rg = 0; rg < 4; ++rg)
            afr[rg] = *(const short8*)&As[(wr + rg * 16 + m16) * STR + q * 8];
        #pragma unroll
        for (int cg = 0; cg < 4; ++cg)
            bfr[cg] = *(const short8*)&Bs[(wc + cg * 16 + m16) * STR + q * 8];
        #pragma unroll
        for (int rg = 0; rg < 4; ++rg)
            #pragma unroll
            for (int cg = 0; cg < 4; ++cg)
                acc[rg][cg] = __builtin_amdgcn_mfma_f32_16x16x32_bf16(
                    afr[rg], bfr[cg], acc[rg][cg], 0, 0, 0);
        __syncthreads();
    }

    #pragma unroll
    for (int rg = 0; rg < 4; ++rg) {
        #pragma unroll
        for (int r = 0; r < 4; ++r) {
            int gr = row0 + wr + rg * 16 + q * 4 + r;
            if (gr < N) {
                float*          cp = C  + (size_t)gr * M + col0 + wc + m16;
                unsigned short* bp = Cb + (size_t)gr * M + col0 + wc + m16;
                #pragma unroll
                for (int cg = 0; cg < 4; ++cg) {
                    float v = acc[rg][cg][r];
                    cp[cg * 16] = v;
                    bp[cg * 16] = f2b(v);
                }
            }
        }
    }
}

// ---------------- MFMA GEMM (M=64): 256x64 block tile, 4 waves stacked ----

__global__ __launch_bounds__(256)
void k_gemm_mfma64(const float* __restrict__ A, const unsigned short* __restrict__ Wt,
                   float* __restrict__ C, unsigned short* __restrict__ Cb,
                   int N, int K) {
    constexpr int M = 64;
    constexpr int STR = 40;
    __shared__ unsigned short As[256 * STR];   // 20 KB
    __shared__ unsigned short Bs[64 * STR];    // 5 KB
    const int tid  = threadIdx.x;
    const int wave = tid >> 6;
    const int lane = tid & 63;
    const int row0 = blockIdx.x * 256;
    const int wr = wave * 64;
    const int m16 = lane & 15;
    const int q   = lane >> 4;

    const int s_row = tid >> 2;          // 0..63 (+64*p)
    const int s_chk = (tid & 3) * 8;

    f32x4 acc[4][4] = {};

    for (int k0 = 0; k0 < K; k0 += 32) {
        #pragma unroll
        for (int p = 0; p < 4; ++p) {
            int r = s_row + p * 64;
            int gr = row0 + r;
            float4 v0 = make_float4(0.f, 0.f, 0.f, 0.f);
            float4 v1 = make_float4(0.f, 0.f, 0.f, 0.f);
            if (gr < N) {
                const float* ap = A + (size_t)gr * K + k0 + s_chk;
                v0 = *(const float4*)ap;
                v1 = *(const float4*)(ap + 4);
            }
            short8 pk;
            pk[0] = (short)f2b(v0.x); pk[1] = (short)f2b(v0.y);
            pk[2] = (short)f2b(v0.z); pk[3] = (short)f2b(v0.w);
            pk[4] = (short)f2b(v1.x); pk[5] = (short)f2b(v1.y);
            pk[6] = (short)f2b(v1.z); pk[7] = (short)f2b(v1.w);
            *(short8*)&As[r * STR + s_chk] = pk;
        }
        {
            // B: 64 m-rows x 32 k
            const unsigned short* sp = Wt + (size_t)s_row * K + k0 + s_chk;
            *(short8*)&Bs[s_row * STR + s_chk] = *(const short8*)sp;
        }
        __syncthreads();

        short8 afr[4], bfr[4];
        #pragma unroll
        for (int rg = 0; rg < 4; ++rg)
            afr[rg] = *(const short8*)&As[(wr + rg * 16 + m16) * STR + q * 8];
        #pragma unroll
        for (int cg = 0; cg < 4; ++cg)
            bfr[cg] = *(const short8*)&Bs[(cg * 16 + m16) * STR + q * 8];
        #pragma unroll
        for (int rg = 0; rg < 4; ++rg)
            #pragma unroll
            for (int cg = 0; cg < 4; ++cg)
                acc[rg][cg] = __builtin_amdgcn_mfma_f32_16x16x32_bf16(
                    afr[rg], bfr[cg], acc[rg][cg], 0, 0, 0);
        __syncthreads();
    }

    #pragma unroll
    for (int rg = 0; rg < 4; ++rg) {
        #pragma unroll
        for (int r = 0; r < 4; ++r) {
            int gr = row0 + wr + rg * 16 + q * 4 + r;
            if (gr < N) {
                float*          cp = C  + (size_t)gr * M + m16;
                unsigned short* bp = Cb + (size_t)gr * M + m16;
                #pragma unroll
                for (int cg = 0; cg < 4; ++cg) {
                    float v = acc[rg][cg][r];
                    cp[cg * 16] = v;
                    bp[cg * 16] = f2b(v);
                }
            }
        }
    }
}

// ---------------- attention pieces (CSR, atomic-free) ----------------

__global__ __launch_bounds__(256)
void k_el_er(const float* __restrict__ feat, const float* __restrict__ al,
             const float* __restrict__ ar, float* __restrict__ el,
             float* __restrict__ er, int NH, int H) {
    int g = blockIdx.x * 4 + (threadIdx.x >> 6);
    int lane = threadIdx.x & 63;
    if (g >= NH) return;
    int h = g % H;
    float v  = feat[(size_t)g * 64 + lane];
    float sl = v * al[h * 64 + lane];
    float sr = v * ar[h * 64 + lane];
    #pragma unroll
    for (int off = 32; off; off >>= 1) {
        sl += __shfl_down(sl, off, 64);
        sr += __shfl_down(sr, off, 64);
    }
    if (lane == 0) { el[g] = sl; er[g] = sr; }
}

// per (node, head): online softmax, then write normalized w per sorted edge
__global__ void k_node_msw(const int* __restrict__ row_start, const int* __restrict__ src_sorted,
                           const float* __restrict__ el, const float* __restrict__ er,
                           float* __restrict__ w, int N, int H) {
    int idx = blockIdx.x * blockDim.x + threadIdx.x;
    if (idx >= N * H) return;
    int n = idx / H;
    int h = idx - n * H;
    float erv = er[idx];
    int b0 = row_start[n], b1 = row_start[n + 1];
    float mx = -INFINITY, sum = 0.f;
    for (int i = b0; i < b1; ++i) {
        float x = el[src_sorted[i] * H + h] + erv;
        x = (x > 0.f) ? x : LEAKY * x;
        if (x > mx) { sum = sum * __expf(mx - x) + 1.f; mx = x; }
        else        { sum += __expf(x - mx); }
    }
    float rs = 1.0f / fmaxf(sum, 1e-30f);
    for (int i = b0; i < b1; ++i) {
        float x = el[src_sorted[i] * H + h] + erv;
        x = (x > 0.f) ? x : LEAKY * x;
        w[(size_t)i * H + h] = __expf(x - mx) * rs;
    }
}

// Aggregation, packed bf16 pairs: thread owns slots (2t, 2t+1), loads one
// uint (2 bf16) per edge. P = M/2 threads per node, G = 256/P nodes/block.
__global__ __launch_bounds__(256)
void k_agg_b(const int* __restrict__ row_start, const int* __restrict__ src_sorted,
             const unsigned* __restrict__ featp, const float* __restrict__ w,
             const float* __restrict__ bias, float* __restrict__ out,
             int H, int N, int do_relu) {
    const int M = H * 64;
    const int P = M >> 1;
    const int G = 256 / P;
    const int grp = threadIdx.x / P;
    const int t = threadIdx.x - grp * P;
    const int n = blockIdx.x * G + grp;
    if (n >= N) return;
    const int d0 = t * 2;
    const int h = d0 >> 6;

    float acc0 = bias[d0], acc1 = bias[d0 + 1];
    int b0 = row_start[n], b1 = row_start[n + 1];
    int i = b0;
    for (; i + 8 <= b1; i += 8) {
        int ss[8]; float wv[8]; unsigned pv[8];
        #pragma unroll
        for (int j = 0; j < 8; ++j) ss[j] = src_sorted[i + j];
        #pragma unroll
        for (int j = 0; j < 8; ++j) wv[j] = w[(size_t)(i + j) * H + h];
        #pragma unroll
        for (int j = 0; j < 8; ++j) pv[j] = featp[(size_t)ss[j] * P + t];
        #pragma unroll
        for (int j = 0; j < 8; ++j) {
            float lo = __uint_as_float(pv[j] << 16);
            float hi = __uint_as_float(pv[j] & 0xFFFF0000u);
            acc0 = fmaf(lo, wv[j], acc0);
            acc1 = fmaf(hi, wv[j], acc1);
        }
    }
    for (; i + 4 <= b1; i += 4) {
        int ss[4]; float wv[4]; unsigned pv[4];
        #pragma unroll
        for (int j = 0; j < 4; ++j) ss[j] = src_sorted[i + j];
        #pragma unroll
        for (int j = 0; j < 4; ++j) wv[j] = w[(size_t)(i + j) * H + h];
        #pragma unroll
        for (int j = 0; j < 4; ++j) pv[j] = featp[(size_t)ss[j] * P + t];
        #pragma unroll
        for (int j = 0; j < 4; ++j) {
            float lo = __uint_as_float(pv[j] << 16);
            float hi = __uint_as_float(pv[j] & 0xFFFF0000u);
            acc0 = fmaf(lo, wv[j], acc0);
            acc1 = fmaf(hi, wv[j], acc1);
        }
    }
    for (; i < b1; ++i) {
        unsigned pv = featp[(size_t)src_sorted[i] * P + t];
        float wv = w[(size_t)i * H + h];
        acc0 = fmaf(__uint_as_float(pv << 16), wv, acc0);
        acc1 = fmaf(__uint_as_float(pv & 0xFFFF0000u), wv, acc1);
    }
    if (do_relu) { acc0 = fmaxf(acc0, 0.f); acc1 = fmaxf(acc1, 0.f); }
    *(float2*)(out + (size_t)n * M + d0) = make_float2(acc0, acc1);
}

// ---------------- host side ----------------

static void run_layer(const float* A, int K, const float* W, unsigned short* Wt,
                      const float* al_, const float* ar_, const float* b_, int H,
                      float* feat, unsigned short* featb, float* rstOut,
                      float* el, float* er, float* w,
                      const int* row_start, const int* src_sorted,
                      int N, int E, bool do_relu, hipStream_t stream) {
    const int M = H * 64;
    k_wt<<<(K * M + 255) / 256, 256, 0, stream>>>(W, Wt, K, M);
    if (M % 128 == 0) {
        dim3 gg(M / 128, (N + 127) / 128);
        k_gemm_mfma<<<gg, 256, 0, stream>>>(A, Wt, feat, featb, N, K, M);
    } else {
        k_gemm_mfma64<<<(N + 255) / 256, 256, 0, stream>>>(A, Wt, feat, featb, N, K);
    }

    int nh = N * H;
    k_el_er<<<(nh + 3) / 4, 256, 0, stream>>>(feat, al_, ar_, el, er, nh, H);
    k_node_msw<<<(nh + 255) / 256, 256, 0, stream>>>(row_start, src_sorted, el, er, w, N, H);

    int G = 256 / (M / 2);
    k_agg_b<<<(N + G - 1) / G, 256, 0, stream>>>(row_start, src_sorted,
                                                 (const unsigned*)featb, w,
                                                 b_, rstOut, H, N, do_relu ? 1 : 0);
}

extern "C" void kernel_launch(void* const* d_in, const int* in_sizes, int n_in,
                              void* d_out, int out_size, void* d_ws, size_t ws_size,
                              hipStream_t stream) {
    const float* features = (const float*)d_in[0];
    const int*   src = (const int*)d_in[1];
    const int*   dst = (const int*)d_in[2];
    const float* W1  = (const float*)d_in[3];
    const float* al1 = (const float*)d_in[4];
    const float* ar1 = (const float*)d_in[5];
    const float* b1  = (const float*)d_in[6];
    const float* W2  = (const float*)d_in[7];
    const float* al2 = (const float*)d_in[8];
    const float* ar2 = (const float*)d_in[9];
    const float* b2  = (const float*)d_in[10];
    const float* W3  = (const float*)d_in[11];
    const float* al3 = (const float*)d_in[12];
    const float* ar3 = (const float*)d_in[13];
    const float* b3  = (const float*)d_in[14];

    const int N = in_sizes[0] / 128;   // 50000
    const int E = in_sizes[1];         // 800000

    float* ws   = (float*)d_ws;
    size_t n256 = (size_t)N * 256;
    float* bufA = ws;                        // [N,256]
    float* bufB = bufA + n256;               // [N,256]
    float* el   = bufB + n256;               // [N,4]
    float* er   = el + (size_t)N * 4;        // [N,4]
    float* w    = er + (size_t)N * 4;        // [E,4]
    int* cnt        = (int*)(w + (size_t)E * 4);   // [N]
    int* row_start  = cnt + N;                      // [N+1]
    int* cursor     = row_start + N + 1;            // [N]
    int* src_sorted = cursor + N;                   // [E]
    uintptr_t wp = (uintptr_t)(src_sorted + E);
    wp = (wp + 15) & ~(uintptr_t)15;
    unsigned short* Wt = (unsigned short*)wp;       // [256*256] bf16 max
    unsigned short* featb = Wt + 256 * 256;         // [N,256] bf16 shadow of feat

    // ---- build dst-CSR (every call; deterministic, graph-capture safe) ----
    k_zero_int<<<(N + 255) / 256, 256, 0, stream>>>(cnt, N);
    k_hist<<<(E + 255) / 256, 256, 0, stream>>>(dst, cnt, E, N);
    k_scan<<<1, 1024, 0, stream>>>(cnt, row_start, cursor, N);
    k_scatter<<<(E + 255) / 256, 256, 0, stream>>>(src, dst, cursor, src_sorted, E, N);

    // layer 1: A=features[N,128] -> feat=bufB[N,256] -> rst=bufA[N,256] (+relu)
    run_layer(features, 128, W1, Wt, al1, ar1, b1, 4, bufB, featb, bufA,
              el, er, w, row_start, src_sorted, N, E, true, stream);
    // layer 2
    run_layer(bufA, 256, W2, Wt, al2, ar2, b2, 4, bufB, featb, bufA,
              el, er, w, row_start, src_sorted, N, E, true, stream);
    // layer 3: H=1; mean over 1 head is identity -> write straight to d_out
    run_layer(bufA, 256, W3, Wt, al3, ar3, b3, 1, bufB, featb, (float*)d_out,
              el, er, w, row_start, src_sorted, N, E, false, stream);
}

// Round 12
// 603.642 us; speedup vs baseline: 2.4424x; 1.0770x over previous
//
#include <hip/hip_runtime.h>
#include <hip/hip_bf16.h>

#define LEAKY 0.2f

typedef __attribute__((ext_vector_type(8))) short short8;
typedef __attribute__((ext_vector_type(4))) float f32x4;

// round-to-nearest-even float -> bf16 bits (finite inputs)
__device__ inline unsigned short f2b(float f) {
    unsigned u = __float_as_uint(f);
    u += 0x7FFFu + ((u >> 16) & 1u);
    return (unsigned short)(u >> 16);
}

// ---------------- CSR build ----------------

__global__ void k_zero_int(int* __restrict__ p, int n) {
    int i = blockIdx.x * blockDim.x + threadIdx.x;
    if (i < n) p[i] = 0;
}

__global__ void k_hist(const int* __restrict__ dst, int* __restrict__ cnt, int E, int N) {
    int e = blockIdx.x * blockDim.x + threadIdx.x;
    if (e >= E) return;
    int dn = dst[e];
    if ((unsigned)dn < (unsigned)N) atomicAdd(&cnt[dn], 1);
}

// ---- parallel 3-phase exclusive scan over cnt[0..N) ----
// phase 1: per-256-block sums
__global__ __launch_bounds__(256)
void k_bsum(const int* __restrict__ cnt, int* __restrict__ bsum, int N) {
    __shared__ int ws[4];
    int i = blockIdx.x * 256 + threadIdx.x;
    int lane = threadIdx.x & 63, wave = threadIdx.x >> 6;
    int v = (i < N) ? cnt[i] : 0;
    #pragma unroll
    for (int off = 32; off; off >>= 1) v += __shfl_down(v, off, 64);
    if (lane == 0) ws[wave] = v;
    __syncthreads();
    if (threadIdx.x == 0)
        bsum[blockIdx.x] = ws[0] + ws[1] + ws[2] + ws[3];
}

// phase 2: single-block exclusive scan of NB (<=256) block sums; writes total
__global__ __launch_bounds__(256)
void k_scan_bsum(const int* __restrict__ bsum, int* __restrict__ boffs,
                 int* __restrict__ row_start_N, int NB) {
    __shared__ int ws[4];
    int tid = threadIdx.x, lane = tid & 63, wave = tid >> 6;
    int v = (tid < NB) ? bsum[tid] : 0;
    int x = v;
    #pragma unroll
    for (int off = 1; off < 64; off <<= 1) {
        int t = __shfl_up(x, off, 64);
        if (lane >= off) x += t;
    }
    if (lane == 63) ws[wave] = x;
    __syncthreads();
    if (tid == 0) {
        int c = 0;
        #pragma unroll
        for (int wv = 0; wv < 4; ++wv) { int t = ws[wv]; ws[wv] = c; c += t; }
    }
    __syncthreads();
    int excl = x - v + ws[wave];
    if (tid < NB) boffs[tid] = excl;
    if (tid == NB - 1) *row_start_N = excl + v;
}

// phase 3: per-block rescan + global offset; writes row_start & cursor
__global__ __launch_bounds__(256)
void k_scan_write(const int* __restrict__ cnt, const int* __restrict__ boffs,
                  int* __restrict__ row_start, int* __restrict__ cursor, int N) {
    __shared__ int ws[4];
    int i = blockIdx.x * 256 + threadIdx.x;
    int tid = threadIdx.x, lane = tid & 63, wave = tid >> 6;
    int v = (i < N) ? cnt[i] : 0;
    int x = v;
    #pragma unroll
    for (int off = 1; off < 64; off <<= 1) {
        int t = __shfl_up(x, off, 64);
        if (lane >= off) x += t;
    }
    if (lane == 63) ws[wave] = x;
    __syncthreads();
    if (tid == 0) {
        int c = 0;
        #pragma unroll
        for (int wv = 0; wv < 4; ++wv) { int t = ws[wv]; ws[wv] = c; c += t; }
    }
    __syncthreads();
    int excl = x - v + ws[wave] + boffs[blockIdx.x];
    if (i < N) { row_start[i] = excl; cursor[i] = excl; }
}

__global__ void k_scatter(const int* __restrict__ src, const int* __restrict__ dst,
                          int* __restrict__ cursor, int* __restrict__ src_sorted,
                          int E, int N) {
    int e = blockIdx.x * blockDim.x + threadIdx.x;
    if (e >= E) return;
    int dn = dst[e];
    if ((unsigned)dn >= (unsigned)N) return;
    int pos = atomicAdd(&cursor[dn], 1);
    src_sorted[pos] = src[e];
}

// ---------------- weight pre-transpose to bf16: Wt[m][k] = bf16(W[k][m]) ----

__global__ void k_wt(const float* __restrict__ W, unsigned short* __restrict__ Wt,
                     int K, int M) {
    int idx = blockIdx.x * blockDim.x + threadIdx.x;
    if (idx >= K * M) return;
    int mcol = idx / K;
    int k = idx - mcol * K;
    Wt[idx] = f2b(W[(size_t)k * M + mcol]);
}

// ---------------- MFMA GEMM (BN=128): C[N,M]=A[N,K]*W[K,M], bf16 in/fp32 acc

__global__ __launch_bounds__(256)
void k_gemm_mfma(const float* __restrict__ A, const unsigned short* __restrict__ Wt,
                 float* __restrict__ C, unsigned short* __restrict__ Cb,
                 int N, int K, int M) {
    constexpr int STR = 40;
    __shared__ unsigned short As[128 * STR];
    __shared__ unsigned short Bs[128 * STR];
    const int tid  = threadIdx.x;
    const int wave = tid >> 6;
    const int lane = tid & 63;
    const int row0 = blockIdx.y * 128;
    const int col0 = blockIdx.x * 128;
    const int wr = (wave >> 1) * 64;
    const int wc = (wave & 1) * 64;
    const int m16 = lane & 15;
    const int q   = lane >> 4;

    const int s_row = tid >> 2;
    const int s_chk = (tid & 3) * 8;
    const int b_row = tid >> 1;
    const int b_off = (tid & 1) * 16;

    f32x4 acc[4][4] = {};

    for (int k0 = 0; k0 < K; k0 += 32) {
        #pragma unroll
        for (int p = 0; p < 2; ++p) {
            int r = s_row + p * 64;
            int gr = row0 + r;
            float4 v0 = make_float4(0.f, 0.f, 0.f, 0.f);
            float4 v1 = make_float4(0.f, 0.f, 0.f, 0.f);
            if (gr < N) {
                const float* ap = A + (size_t)gr * K + k0 + s_chk;
                v0 = *(const float4*)ap;
                v1 = *(const float4*)(ap + 4);
            }
            short8 pk;
            pk[0] = (short)f2b(v0.x); pk[1] = (short)f2b(v0.y);
            pk[2] = (short)f2b(v0.z); pk[3] = (short)f2b(v0.w);
            pk[4] = (short)f2b(v1.x); pk[5] = (short)f2b(v1.y);
            pk[6] = (short)f2b(v1.z); pk[7] = (short)f2b(v1.w);
            *(short8*)&As[r * STR + s_chk] = pk;
        }
        {
            const unsigned short* sp = Wt + (size_t)(col0 + b_row) * K + k0 + b_off;
            *(short8*)&Bs[b_row * STR + b_off]     = *(const short8*)sp;
            *(short8*)&Bs[b_row * STR + b_off + 8] = *(const short8*)(sp + 8);
        }
        __syncthreads();

        short8 afr[4], bfr[4];
        #pragma unroll
        for (int rg = 0; rg < 4; ++rg)
            afr[rg] = *(const short8*)&As[(wr + rg * 16 + m16) * STR + q * 8];
        #pragma unroll
        for (int cg = 0; cg < 4; ++cg)
            bfr[cg] = *(const short8*)&Bs[(wc + cg * 16 + m16) * STR + q * 8];
        #pragma unroll
        for (int rg = 0; rg < 4; ++rg)
            #pragma unroll
            for (int cg = 0; cg < 4; ++cg)
                acc[rg][cg] = __builtin_amdgcn_mfma_f32_16x16x32_bf16(
                    afr[rg], bfr[cg], acc[rg][cg], 0, 0, 0);
        __syncthreads();
    }

    #pragma unroll
    for (int rg = 0; rg < 4; ++rg) {
        #pragma unroll
        for (int r = 0; r < 4; ++r) {
            int gr = row0 + wr + rg * 16 + q * 4 + r;
            if (gr < N) {
                float*          cp = C  + (size_t)gr * M + col0 + wc + m16;
                unsigned short* bp = Cb + (size_t)gr * M + col0 + wc + m16;
                #pragma unroll
                for (int cg = 0; cg < 4; ++cg) {
                    float v = acc[rg][cg][r];
                    cp[cg * 16] = v;
                    bp[cg * 16] = f2b(v);
                }
            }
        }
    }
}

// ---------------- MFMA GEMM (M=64): 256x64 block tile, 4 waves stacked ----

__global__ __launch_bounds__(256)
void k_gemm_mfma64(const float* __restrict__ A, const unsigned short* __restrict__ Wt,
                   float* __restrict__ C, unsigned short* __restrict__ Cb,
                   int N, int K) {
    constexpr int M = 64;
    constexpr int STR = 40;
    __shared__ unsigned short As[256 * STR];
    __shared__ unsigned short Bs[64 * STR];
    const int tid  = threadIdx.x;
    const int wave = tid >> 6;
    const int lane = tid & 63;
    const int row0 = blockIdx.x * 256;
    const int wr = wave * 64;
    const int m16 = lane & 15;
    const int q   = lane >> 4;

    const int s_row = tid >> 2;
    const int s_chk = (tid & 3) * 8;

    f32x4 acc[4][4] = {};

    for (int k0 = 0; k0 < K; k0 += 32) {
        #pragma unroll
        for (int p = 0; p < 4; ++p) {
            int r = s_row + p * 64;
            int gr = row0 + r;
            float4 v0 = make_float4(0.f, 0.f, 0.f, 0.f);
            float4 v1 = make_float4(0.f, 0.f, 0.f, 0.f);
            if (gr < N) {
                const float* ap = A + (size_t)gr * K + k0 + s_chk;
                v0 = *(const float4*)ap;
                v1 = *(const float4*)(ap + 4);
            }
            short8 pk;
            pk[0] = (short)f2b(v0.x); pk[1] = (short)f2b(v0.y);
            pk[2] = (short)f2b(v0.z); pk[3] = (short)f2b(v0.w);
            pk[4] = (short)f2b(v1.x); pk[5] = (short)f2b(v1.y);
            pk[6] = (short)f2b(v1.z); pk[7] = (short)f2b(v1.w);
            *(short8*)&As[r * STR + s_chk] = pk;
        }
        {
            const unsigned short* sp = Wt + (size_t)s_row * K + k0 + s_chk;
            *(short8*)&Bs[s_row * STR + s_chk] = *(const short8*)sp;
        }
        __syncthreads();

        short8 afr[4], bfr[4];
        #pragma unroll
        for (int rg = 0; rg < 4; ++rg)
            afr[rg] = *(const short8*)&As[(wr + rg * 16 + m16) * STR + q * 8];
        #pragma unroll
        for (int cg = 0; cg < 4; ++cg)
            bfr[cg] = *(const short8*)&Bs[(cg * 16 + m16) * STR + q * 8];
        #pragma unroll
        for (int rg = 0; rg < 4; ++rg)
            #pragma unroll
            for (int cg = 0; cg < 4; ++cg)
                acc[rg][cg] = __builtin_amdgcn_mfma_f32_16x16x32_bf16(
                    afr[rg], bfr[cg], acc[rg][cg], 0, 0, 0);
        __syncthreads();
    }

    #pragma unroll
    for (int rg = 0; rg < 4; ++rg) {
        #pragma unroll
        for (int r = 0; r < 4; ++r) {
            int gr = row0 + wr + rg * 16 + q * 4 + r;
            if (gr < N) {
                float*          cp = C  + (size_t)gr * M + m16;
                unsigned short* bp = Cb + (size_t)gr * M + m16;
                #pragma unroll
                for (int cg = 0; cg < 4; ++cg) {
                    float v = acc[rg][cg][r];
                    cp[cg * 16] = v;
                    bp[cg * 16] = f2b(v);
                }
            }
        }
    }
}

// ---------------- attention pieces (CSR, atomic-free) ----------------

__global__ __launch_bounds__(256)
void k_el_er(const float* __restrict__ feat, const float* __restrict__ al,
             const float* __restrict__ ar, float* __restrict__ el,
             float* __restrict__ er, int NH, int H) {
    int g = blockIdx.x * 4 + (threadIdx.x >> 6);
    int lane = threadIdx.x & 63;
    if (g >= NH) return;
    int h = g % H;
    float v  = feat[(size_t)g * 64 + lane];
    float sl = v * al[h * 64 + lane];
    float sr = v * ar[h * 64 + lane];
    #pragma unroll
    for (int off = 32; off; off >>= 1) {
        sl += __shfl_down(sl, off, 64);
        sr += __shfl_down(sr, off, 64);
    }
    if (lane == 0) { el[g] = sl; er[g] = sr; }
}

// per (node, head): online softmax, then write normalized w per sorted edge
__global__ void k_node_msw(const int* __restrict__ row_start, const int* __restrict__ src_sorted,
                           const float* __restrict__ el, const float* __restrict__ er,
                           float* __restrict__ w, int N, int H) {
    int idx = blockIdx.x * blockDim.x + threadIdx.x;
    if (idx >= N * H) return;
    int n = idx / H;
    int h = idx - n * H;
    float erv = er[idx];
    int b0 = row_start[n], b1 = row_start[n + 1];
    float mx = -INFINITY, sum = 0.f;
    for (int i = b0; i < b1; ++i) {
        float x = el[src_sorted[i] * H + h] + erv;
        x = (x > 0.f) ? x : LEAKY * x;
        if (x > mx) { sum = sum * __expf(mx - x) + 1.f; mx = x; }
        else        { sum += __expf(x - mx); }
    }
    float rs = 1.0f / fmaxf(sum, 1e-30f);
    for (int i = b0; i < b1; ++i) {
        float x = el[src_sorted[i] * H + h] + erv;
        x = (x > 0.f) ? x : LEAKY * x;
        w[(size_t)i * H + h] = __expf(x - mx) * rs;
    }
}

// Aggregation, packed bf16 quads: thread owns slots (4t..4t+3), loads one
// uint2 (4 bf16) per edge. P = M/4 threads per node, G = 256/P nodes/block.
__global__ __launch_bounds__(256)
void k_agg_b(const int* __restrict__ row_start, const int* __restrict__ src_sorted,
             const uint2* __restrict__ featp, const float* __restrict__ w,
             const float* __restrict__ bias, float* __restrict__ out,
             int H, int N, int do_relu) {
    const int M = H * 64;
    const int P = M >> 2;
    const int G = 256 / P;
    const int grp = threadIdx.x / P;
    const int t = threadIdx.x - grp * P;
    const int n = blockIdx.x * G + grp;
    if (n >= N) return;
    const int d0 = t * 4;
    const int h = d0 >> 6;

    float4 bv = *(const float4*)(bias + d0);
    float a0 = bv.x, a1 = bv.y, a2 = bv.z, a3 = bv.w;
    int b0 = row_start[n], b1 = row_start[n + 1];
    int i = b0;
    for (; i + 8 <= b1; i += 8) {
        int ss[8]; float wv[8]; uint2 pv[8];
        #pragma unroll
        for (int j = 0; j < 8; ++j) ss[j] = src_sorted[i + j];
        #pragma unroll
        for (int j = 0; j < 8; ++j) wv[j] = w[(size_t)(i + j) * H + h];
        #pragma unroll
        for (int j = 0; j < 8; ++j) pv[j] = featp[(size_t)ss[j] * P + t];
        #pragma unroll
        for (int j = 0; j < 8; ++j) {
            a0 = fmaf(__uint_as_float(pv[j].x << 16), wv[j], a0);
            a1 = fmaf(__uint_as_float(pv[j].x & 0xFFFF0000u), wv[j], a1);
            a2 = fmaf(__uint_as_float(pv[j].y << 16), wv[j], a2);
            a3 = fmaf(__uint_as_float(pv[j].y & 0xFFFF0000u), wv[j], a3);
        }
    }
    for (; i + 4 <= b1; i += 4) {
        int ss[4]; float wv[4]; uint2 pv[4];
        #pragma unroll
        for (int j = 0; j < 4; ++j) ss[j] = src_sorted[i + j];
        #pragma unroll
        for (int j = 0; j < 4; ++j) wv[j] = w[(size_t)(i + j) * H + h];
        #pragma unroll
        for (int j = 0; j < 4; ++j) pv[j] = featp[(size_t)ss[j] * P + t];
        #pragma unroll
        for (int j = 0; j < 4; ++j) {
            a0 = fmaf(__uint_as_float(pv[j].x << 16), wv[j], a0);
            a1 = fmaf(__uint_as_float(pv[j].x & 0xFFFF0000u), wv[j], a1);
            a2 = fmaf(__uint_as_float(pv[j].y << 16), wv[j], a2);
            a3 = fmaf(__uint_as_float(pv[j].y & 0xFFFF0000u), wv[j], a3);
        }
    }
    for (; i < b1; ++i) {
        uint2 pv = featp[(size_t)src_sorted[i] * P + t];
        float wv = w[(size_t)i * H + h];
        a0 = fmaf(__uint_as_float(pv.x << 16), wv, a0);
        a1 = fmaf(__uint_as_float(pv.x & 0xFFFF0000u), wv, a1);
        a2 = fmaf(__uint_as_float(pv.y << 16), wv, a2);
        a3 = fmaf(__uint_as_float(pv.y & 0xFFFF0000u), wv, a3);
    }
    if (do_relu) {
        a0 = fmaxf(a0, 0.f); a1 = fmaxf(a1, 0.f);
        a2 = fmaxf(a2, 0.f); a3 = fmaxf(a3, 0.f);
    }
    *(float4*)(out + (size_t)n * M + d0) = make_float4(a0, a1, a2, a3);
}

// ---------------- host side ----------------

static void run_layer(const float* A, int K, const float* W, unsigned short* Wt,
                      const float* al_, const float* ar_, const float* b_, int H,
                      float* feat, unsigned short* featb, float* rstOut,
                      float* el, float* er, float* w,
                      const int* row_start, const int* src_sorted,
                      int N, int E, bool do_relu, hipStream_t stream) {
    const int M = H * 64;
    k_wt<<<(K * M + 255) / 256, 256, 0, stream>>>(W, Wt, K, M);
    if (M % 128 == 0) {
        dim3 gg(M / 128, (N + 127) / 128);
        k_gemm_mfma<<<gg, 256, 0, stream>>>(A, Wt, feat, featb, N, K, M);
    } else {
        k_gemm_mfma64<<<(N + 255) / 256, 256, 0, stream>>>(A, Wt, feat, featb, N, K);
    }

    int nh = N * H;
    k_el_er<<<(nh + 3) / 4, 256, 0, stream>>>(feat, al_, ar_, el, er, nh, H);
    k_node_msw<<<(nh + 255) / 256, 256, 0, stream>>>(row_start, src_sorted, el, er, w, N, H);

    int G = 256 / (M / 4);
    k_agg_b<<<(N + G - 1) / G, 256, 0, stream>>>(row_start, src_sorted,
                                                 (const uint2*)featb, w,
                                                 b_, rstOut, H, N, do_relu ? 1 : 0);
}

extern "C" void kernel_launch(void* const* d_in, const int* in_sizes, int n_in,
                              void* d_out, int out_size, void* d_ws, size_t ws_size,
                              hipStream_t stream) {
    const float* features = (const float*)d_in[0];
    const int*   src = (const int*)d_in[1];
    const int*   dst = (const int*)d_in[2];
    const float* W1  = (const float*)d_in[3];
    const float* al1 = (const float*)d_in[4];
    const float* ar1 = (const float*)d_in[5];
    const float* b1  = (const float*)d_in[6];
    const float* W2  = (const float*)d_in[7];
    const float* al2 = (const float*)d_in[8];
    const float* ar2 = (const float*)d_in[9];
    const float* b2  = (const float*)d_in[10];
    const float* W3  = (const float*)d_in[11];
    const float* al3 = (const float*)d_in[12];
    const float* ar3 = (const float*)d_in[13];
    const float* b3  = (const float*)d_in[14];

    const int N = in_sizes[0] / 128;   // 50000
    const int E = in_sizes[1];         // 800000
    const int NB = (N + 255) / 256;    // scan blocks (196)

    float* ws   = (float*)d_ws;
    size_t n256 = (size_t)N * 256;
    float* bufA = ws;                        // [N,256]
    float* bufB = bufA + n256;               // [N,256]
    float* el   = bufB + n256;               // [N,4]
    float* er   = el + (size_t)N * 4;        // [N,4]
    float* w    = er + (size_t)N * 4;        // [E,4]
    int* cnt        = (int*)(w + (size_t)E * 4);   // [N]
    int* row_start  = cnt + N;                      // [N+1]
    int* cursor     = row_start + N + 1;            // [N]
    int* src_sorted = cursor + N;                   // [E]
    int* bsum       = src_sorted + E;               // [NB]
    int* boffs      = bsum + NB;                    // [NB]
    uintptr_t wp = (uintptr_t)(boffs + NB);
    wp = (wp + 15) & ~(uintptr_t)15;
    unsigned short* Wt = (unsigned short*)wp;       // [256*256] bf16 max
    unsigned short* featb = Wt + 256 * 256;         // [N,256] bf16 shadow of feat

    // ---- build dst-CSR (every call; deterministic, graph-capture safe) ----
    k_zero_int<<<(N + 255) / 256, 256, 0, stream>>>(cnt, N);
    k_hist<<<(E + 255) / 256, 256, 0, stream>>>(dst, cnt, E, N);
    k_bsum<<<NB, 256, 0, stream>>>(cnt, bsum, N);
    k_scan_bsum<<<1, 256, 0, stream>>>(bsum, boffs, row_start + N, NB);
    k_scan_write<<<NB, 256, 0, stream>>>(cnt, boffs, row_start, cursor, N);
    k_scatter<<<(E + 255) / 256, 256, 0, stream>>>(src, dst, cursor, src_sorted, E, N);

    // layer 1: A=features[N,128] -> feat=bufB[N,256] -> rst=bufA[N,256] (+relu)
    run_layer(features, 128, W1, Wt, al1, ar1, b1, 4, bufB, featb, bufA,
              el, er, w, row_start, src_sorted, N, E, true, stream);
    // layer 2
    run_layer(bufA, 256, W2, Wt, al2, ar2, b2, 4, bufB, featb, bufA,
              el, er, w, row_start, src_sorted, N, E, true, stream);
    // layer 3: H=1; mean over 1 head is identity -> write straight to d_out
    run_layer(bufA, 256, W3, Wt, al3, ar3, b3, 1, bufB, featb, (float*)d_out,
              el, er, w, row_start, src_sorted, N, E, false, stream);
}

// Round 13
// 586.818 us; speedup vs baseline: 2.5124x; 1.0287x over previous
//
#include <hip/hip_runtime.h>
#include <hip/hip_bf16.h>

#define LEAKY 0.2f

typedef __attribute__((ext_vector_type(8))) short short8;
typedef __attribute__((ext_vector_type(4))) float f32x4;

// round-to-nearest-even float -> bf16 bits (finite inputs)
__device__ inline unsigned short f2b(float f) {
    unsigned u = __float_as_uint(f);
    u += 0x7FFFu + ((u >> 16) & 1u);
    return (unsigned short)(u >> 16);
}
__device__ inline float b2f(unsigned short s) {
    return __uint_as_float(((unsigned)s) << 16);
}

// ---------------- misc ----------------

__global__ void k_zero_int(int* __restrict__ p, int n) {
    int i = blockIdx.x * blockDim.x + threadIdx.x;
    if (i < n) p[i] = 0;
}

// fp32 -> bf16 bulk convert (features), 4 elems/thread
__global__ void k_convert(const float* __restrict__ in, unsigned short* __restrict__ out, int n4) {
    int i = blockIdx.x * blockDim.x + threadIdx.x;
    if (i >= n4) return;
    float4 v = *(const float4*)(in + i * 4);
    ushort4 o;
    o.x = f2b(v.x); o.y = f2b(v.y); o.z = f2b(v.z); o.w = f2b(v.w);
    *(ushort4*)(out + i * 4) = o;
}

// ---------------- CSR build ----------------

__global__ void k_hist(const int* __restrict__ dst, int* __restrict__ cnt, int E, int N) {
    int e = blockIdx.x * blockDim.x + threadIdx.x;
    if (e >= E) return;
    int dn = dst[e];
    if ((unsigned)dn < (unsigned)N) atomicAdd(&cnt[dn], 1);
}

__global__ __launch_bounds__(256)
void k_bsum(const int* __restrict__ cnt, int* __restrict__ bsum, int N) {
    __shared__ int ws[4];
    int i = blockIdx.x * 256 + threadIdx.x;
    int lane = threadIdx.x & 63, wave = threadIdx.x >> 6;
    int v = (i < N) ? cnt[i] : 0;
    #pragma unroll
    for (int off = 32; off; off >>= 1) v += __shfl_down(v, off, 64);
    if (lane == 0) ws[wave] = v;
    __syncthreads();
    if (threadIdx.x == 0)
        bsum[blockIdx.x] = ws[0] + ws[1] + ws[2] + ws[3];
}

__global__ __launch_bounds__(256)
void k_scan_bsum(const int* __restrict__ bsum, int* __restrict__ boffs,
                 int* __restrict__ row_start_N, int NB) {
    __shared__ int ws[4];
    int tid = threadIdx.x, lane = tid & 63, wave = tid >> 6;
    int v = (tid < NB) ? bsum[tid] : 0;
    int x = v;
    #pragma unroll
    for (int off = 1; off < 64; off <<= 1) {
        int t = __shfl_up(x, off, 64);
        if (lane >= off) x += t;
    }
    if (lane == 63) ws[wave] = x;
    __syncthreads();
    if (tid == 0) {
        int c = 0;
        #pragma unroll
        for (int wv = 0; wv < 4; ++wv) { int t = ws[wv]; ws[wv] = c; c += t; }
    }
    __syncthreads();
    int excl = x - v + ws[wave];
    if (tid < NB) boffs[tid] = excl;
    if (tid == NB - 1) *row_start_N = excl + v;
}

__global__ __launch_bounds__(256)
void k_scan_write(const int* __restrict__ cnt, const int* __restrict__ boffs,
                  int* __restrict__ row_start, int* __restrict__ cursor, int N) {
    __shared__ int ws[4];
    int i = blockIdx.x * 256 + threadIdx.x;
    int tid = threadIdx.x, lane = tid & 63, wave = tid >> 6;
    int v = (i < N) ? cnt[i] : 0;
    int x = v;
    #pragma unroll
    for (int off = 1; off < 64; off <<= 1) {
        int t = __shfl_up(x, off, 64);
        if (lane >= off) x += t;
    }
    if (lane == 63) ws[wave] = x;
    __syncthreads();
    if (tid == 0) {
        int c = 0;
        #pragma unroll
        for (int wv = 0; wv < 4; ++wv) { int t = ws[wv]; ws[wv] = c; c += t; }
    }
    __syncthreads();
    int excl = x - v + ws[wave] + boffs[blockIdx.x];
    if (i < N) { row_start[i] = excl; cursor[i] = excl; }
}

__global__ void k_scatter(const int* __restrict__ src, const int* __restrict__ dst,
                          int* __restrict__ cursor, int* __restrict__ src_sorted,
                          int E, int N) {
    int e = blockIdx.x * blockDim.x + threadIdx.x;
    if (e >= E) return;
    int dn = dst[e];
    if ((unsigned)dn >= (unsigned)N) return;
    int pos = atomicAdd(&cursor[dn], 1);
    src_sorted[pos] = src[e];
}

// ---------------- weight pre-transpose to bf16: Wt[m][k] = bf16(W[k][m]) ----

__global__ void k_wt(const float* __restrict__ W, unsigned short* __restrict__ Wt,
                     int K, int M) {
    int idx = blockIdx.x * blockDim.x + threadIdx.x;
    if (idx >= K * M) return;
    int mcol = idx / K;
    int k = idx - mcol * K;
    Wt[idx] = f2b(W[(size_t)k * M + mcol]);
}

// ---------------- MFMA GEMM (BN=128): Cb[N,M]=A[N,K]*W[K,M], all-bf16 flow ----
// A bf16 [N,K], Wt bf16 [M,K]; 128x128 tile, 4 waves (2x2); emits bf16 only.

__global__ __launch_bounds__(256)
void k_gemm_mfma(const unsigned short* __restrict__ A, const unsigned short* __restrict__ Wt,
                 unsigned short* __restrict__ Cb, int N, int K, int M) {
    constexpr int STR = 40;
    __shared__ unsigned short As[128 * STR];
    __shared__ unsigned short Bs[128 * STR];
    const int tid  = threadIdx.x;
    const int wave = tid >> 6;
    const int lane = tid & 63;
    const int row0 = blockIdx.y * 128;
    const int col0 = blockIdx.x * 128;
    const int wr = (wave >> 1) * 64;
    const int wc = (wave & 1) * 64;
    const int m16 = lane & 15;
    const int q   = lane >> 4;

    const int s_row = tid >> 1;          // 0..127
    const int s_off = (tid & 1) * 16;    // k offset 0 or 16

    f32x4 acc[4][4] = {};

    for (int k0 = 0; k0 < K; k0 += 32) {
        {
            int gr = row0 + s_row;
            short8 z = {};
            short8 v0 = z, v1 = z;
            if (gr < N) {
                const unsigned short* ap = A + (size_t)gr * K + k0 + s_off;
                v0 = *(const short8*)ap;
                v1 = *(const short8*)(ap + 8);
            }
            *(short8*)&As[s_row * STR + s_off]     = v0;
            *(short8*)&As[s_row * STR + s_off + 8] = v1;
        }
        {
            const unsigned short* sp = Wt + (size_t)(col0 + s_row) * K + k0 + s_off;
            *(short8*)&Bs[s_row * STR + s_off]     = *(const short8*)sp;
            *(short8*)&Bs[s_row * STR + s_off + 8] = *(const short8*)(sp + 8);
        }
        __syncthreads();

        short8 afr[4], bfr[4];
        #pragma unroll
        for (int rg = 0; rg < 4; ++rg)
            afr[rg] = *(const short8*)&As[(wr + rg * 16 + m16) * STR + q * 8];
        #pragma unroll
        for (int cg = 0; cg < 4; ++cg)
            bfr[cg] = *(const short8*)&Bs[(wc + cg * 16 + m16) * STR + q * 8];
        #pragma unroll
        for (int rg = 0; rg < 4; ++rg)
            #pragma unroll
            for (int cg = 0; cg < 4; ++cg)
                acc[rg][cg] = __builtin_amdgcn_mfma_f32_16x16x32_bf16(
                    afr[rg], bfr[cg], acc[rg][cg], 0, 0, 0);
        __syncthreads();
    }

    #pragma unroll
    for (int rg = 0; rg < 4; ++rg) {
        #pragma unroll
        for (int r = 0; r < 4; ++r) {
            int gr = row0 + wr + rg * 16 + q * 4 + r;
            if (gr < N) {
                unsigned short* bp = Cb + (size_t)gr * M + col0 + wc + m16;
                #pragma unroll
                for (int cg = 0; cg < 4; ++cg)
                    bp[cg * 16] = f2b(acc[rg][cg][r]);
            }
        }
    }
}

// ---------------- MFMA GEMM (M=64): 256x64 tile, 4 waves stacked ----

__global__ __launch_bounds__(256)
void k_gemm_mfma64(const unsigned short* __restrict__ A, const unsigned short* __restrict__ Wt,
                   unsigned short* __restrict__ Cb, int N, int K) {
    constexpr int M = 64;
    constexpr int STR = 40;
    __shared__ unsigned short As[256 * STR];
    __shared__ unsigned short Bs[64 * STR];
    const int tid  = threadIdx.x;
    const int wave = tid >> 6;
    const int lane = tid & 63;
    const int row0 = blockIdx.x * 256;
    const int wr = wave * 64;
    const int m16 = lane & 15;
    const int q   = lane >> 4;

    const int s_row = tid >> 1;          // 0..127 (+128 second pass)
    const int s_off = (tid & 1) * 16;
    const int b_row = tid >> 2;          // 0..63
    const int b_chk = (tid & 3) * 8;

    f32x4 acc[4][4] = {};

    for (int k0 = 0; k0 < K; k0 += 32) {
        #pragma unroll
        for (int p = 0; p < 2; ++p) {
            int r = s_row + p * 128;
            int gr = row0 + r;
            short8 z = {};
            short8 v0 = z, v1 = z;
            if (gr < N) {
                const unsigned short* ap = A + (size_t)gr * K + k0 + s_off;
                v0 = *(const short8*)ap;
                v1 = *(const short8*)(ap + 8);
            }
            *(short8*)&As[r * STR + s_off]     = v0;
            *(short8*)&As[r * STR + s_off + 8] = v1;
        }
        {
            const unsigned short* sp = Wt + (size_t)b_row * K + k0 + b_chk;
            *(short8*)&Bs[b_row * STR + b_chk] = *(const short8*)sp;
        }
        __syncthreads();

        short8 afr[4], bfr[4];
        #pragma unroll
        for (int rg = 0; rg < 4; ++rg)
            afr[rg] = *(const short8*)&As[(wr + rg * 16 + m16) * STR + q * 8];
        #pragma unroll
        for (int cg = 0; cg < 4; ++cg)
            bfr[cg] = *(const short8*)&Bs[(cg * 16 + m16) * STR + q * 8];
        #pragma unroll
        for (int rg = 0; rg < 4; ++rg)
            #pragma unroll
            for (int cg = 0; cg < 4; ++cg)
                acc[rg][cg] = __builtin_amdgcn_mfma_f32_16x16x32_bf16(
                    afr[rg], bfr[cg], acc[rg][cg], 0, 0, 0);
        __syncthreads();
    }

    #pragma unroll
    for (int rg = 0; rg < 4; ++rg) {
        #pragma unroll
        for (int r = 0; r < 4; ++r) {
            int gr = row0 + wr + rg * 16 + q * 4 + r;
            if (gr < N) {
                unsigned short* bp = Cb + (size_t)gr * M + m16;
                #pragma unroll
                for (int cg = 0; cg < 4; ++cg)
                    bp[cg * 16] = f2b(acc[rg][cg][r]);
            }
        }
    }
}

// ---------------- attention pieces (CSR, atomic-free) ----------------

// one wave per (node,head), bf16 feat read
__global__ __launch_bounds__(256)
void k_el_er(const unsigned short* __restrict__ featb, const float* __restrict__ al,
             const float* __restrict__ ar, float* __restrict__ el,
             float* __restrict__ er, int NH, int H) {
    int g = blockIdx.x * 4 + (threadIdx.x >> 6);
    int lane = threadIdx.x & 63;
    if (g >= NH) return;
    int h = g % H;
    float v  = b2f(featb[(size_t)g * 64 + lane]);
    float sl = v * al[h * 64 + lane];
    float sr = v * ar[h * 64 + lane];
    #pragma unroll
    for (int off = 32; off; off >>= 1) {
        sl += __shfl_down(sl, off, 64);
        sr += __shfl_down(sr, off, 64);
    }
    if (lane == 0) { el[g] = sl; er[g] = sr; }
}

// per (node, head): pass 1 gathers el once, stores leaky-x into w, tracks max;
// pass 2 exps in place and accumulates sum; s[idx] = 1/sum (applied in agg).
__global__ void k_node_msw(const int* __restrict__ row_start, const int* __restrict__ src_sorted,
                           const float* __restrict__ el, const float* __restrict__ er,
                           float* __restrict__ w, float* __restrict__ s, int N, int H) {
    int idx = blockIdx.x * blockDim.x + threadIdx.x;
    if (idx >= N * H) return;
    int n = idx / H;
    int h = idx - n * H;
    float erv = er[idx];
    int b0 = row_start[n], b1 = row_start[n + 1];
    float mx = -INFINITY;
    for (int i = b0; i < b1; ++i) {
        float x = el[src_sorted[i] * H + h] + erv;
        x = (x > 0.f) ? x : LEAKY * x;
        w[(size_t)i * H + h] = x;
        mx = fmaxf(mx, x);
    }
    float sum = 0.f;
    for (int i = b0; i < b1; ++i) {
        float e = __expf(w[(size_t)i * H + h] - mx);
        sum += e;
        w[(size_t)i * H + h] = e;
    }
    s[idx] = 1.0f / fmaxf(sum, 1e-30f);
}

// Aggregation, packed bf16 quads; unnormalized weights, 1/sum applied at end.
// OUTBF: write bf16 (layers 1-2) or fp32 (layer 3 -> d_out).
template<int OUTBF>
__global__ __launch_bounds__(256)
void k_agg_b(const int* __restrict__ row_start, const int* __restrict__ src_sorted,
             const uint2* __restrict__ featp, const float* __restrict__ w,
             const float* __restrict__ s, const float* __restrict__ bias,
             void* __restrict__ outv, int H, int N, int do_relu) {
    const int M = H * 64;
    const int P = M >> 2;
    const int G = 256 / P;
    const int grp = threadIdx.x / P;
    const int t = threadIdx.x - grp * P;
    const int n = blockIdx.x * G + grp;
    if (n >= N) return;
    const int d0 = t * 4;
    const int h = d0 >> 6;

    float a0 = 0.f, a1 = 0.f, a2 = 0.f, a3 = 0.f;
    int b0 = row_start[n], b1 = row_start[n + 1];
    int i = b0;
    for (; i + 8 <= b1; i += 8) {
        int ss[8]; float wv[8]; uint2 pv[8];
        #pragma unroll
        for (int j = 0; j < 8; ++j) ss[j] = src_sorted[i + j];
        #pragma unroll
        for (int j = 0; j < 8; ++j) wv[j] = w[(size_t)(i + j) * H + h];
        #pragma unroll
        for (int j = 0; j < 8; ++j) pv[j] = featp[(size_t)ss[j] * P + t];
        #pragma unroll
        for (int j = 0; j < 8; ++j) {
            a0 = fmaf(__uint_as_float(pv[j].x << 16), wv[j], a0);
            a1 = fmaf(__uint_as_float(pv[j].x & 0xFFFF0000u), wv[j], a1);
            a2 = fmaf(__uint_as_float(pv[j].y << 16), wv[j], a2);
            a3 = fmaf(__uint_as_float(pv[j].y & 0xFFFF0000u), wv[j], a3);
        }
    }
    for (; i + 4 <= b1; i += 4) {
        int ss[4]; float wv[4]; uint2 pv[4];
        #pragma unroll
        for (int j = 0; j < 4; ++j) ss[j] = src_sorted[i + j];
        #pragma unroll
        for (int j = 0; j < 4; ++j) wv[j] = w[(size_t)(i + j) * H + h];
        #pragma unroll
        for (int j = 0; j < 4; ++j) pv[j] = featp[(size_t)ss[j] * P + t];
        #pragma unroll
        for (int j = 0; j < 4; ++j) {
            a0 = fmaf(__uint_as_float(pv[j].x << 16), wv[j], a0);
            a1 = fmaf(__uint_as_float(pv[j].x & 0xFFFF0000u), wv[j], a1);
            a2 = fmaf(__uint_as_float(pv[j].y << 16), wv[j], a2);
            a3 = fmaf(__uint_as_float(pv[j].y & 0xFFFF0000u), wv[j], a3);
        }
    }
    for (; i < b1; ++i) {
        uint2 pv = featp[(size_t)src_sorted[i] * P + t];
        float wv = w[(size_t)i * H + h];
        a0 = fmaf(__uint_as_float(pv.x << 16), wv, a0);
        a1 = fmaf(__uint_as_float(pv.x & 0xFFFF0000u), wv, a1);
        a2 = fmaf(__uint_as_float(pv.y << 16), wv, a2);
        a3 = fmaf(__uint_as_float(pv.y & 0xFFFF0000u), wv, a3);
    }
    float rs = s[n * H + h];
    float4 bv = *(const float4*)(bias + d0);
    a0 = fmaf(a0, rs, bv.x);
    a1 = fmaf(a1, rs, bv.y);
    a2 = fmaf(a2, rs, bv.z);
    a3 = fmaf(a3, rs, bv.w);
    if (do_relu) {
        a0 = fmaxf(a0, 0.f); a1 = fmaxf(a1, 0.f);
        a2 = fmaxf(a2, 0.f); a3 = fmaxf(a3, 0.f);
    }
    if (OUTBF) {
        ushort4 o;
        o.x = f2b(a0); o.y = f2b(a1); o.z = f2b(a2); o.w = f2b(a3);
        *(ushort4*)((unsigned short*)outv + (size_t)n * M + d0) = o;
    } else {
        *(float4*)((float*)outv + (size_t)n * M + d0) = make_float4(a0, a1, a2, a3);
    }
}

// ---------------- host side ----------------

static void run_layer(const unsigned short* A, int K, const float* W, unsigned short* Wt,
                      const float* al_, const float* ar_, const float* b_, int H,
                      unsigned short* featb, void* rstOut, bool outBf,
                      float* el, float* er, float* w, float* s,
                      const int* row_start, const int* src_sorted,
                      int N, int E, bool do_relu, hipStream_t stream) {
    const int M = H * 64;
    k_wt<<<(K * M + 255) / 256, 256, 0, stream>>>(W, Wt, K, M);
    if (M % 128 == 0) {
        dim3 gg(M / 128, (N + 127) / 128);
        k_gemm_mfma<<<gg, 256, 0, stream>>>(A, Wt, featb, N, K, M);
    } else {
        k_gemm_mfma64<<<(N + 255) / 256, 256, 0, stream>>>(A, Wt, featb, N, K);
    }

    int nh = N * H;
    k_el_er<<<(nh + 3) / 4, 256, 0, stream>>>(featb, al_, ar_, el, er, nh, H);
    k_node_msw<<<(nh + 255) / 256, 256, 0, stream>>>(row_start, src_sorted, el, er, w, s, N, H);

    int G = 256 / (M / 4);
    if (outBf)
        k_agg_b<1><<<(N + G - 1) / G, 256, 0, stream>>>(row_start, src_sorted,
                                                        (const uint2*)featb, w, s,
                                                        b_, rstOut, H, N, do_relu ? 1 : 0);
    else
        k_agg_b<0><<<(N + G - 1) / G, 256, 0, stream>>>(row_start, src_sorted,
                                                        (const uint2*)featb, w, s,
                                                        b_, rstOut, H, N, do_relu ? 1 : 0);
}

extern "C" void kernel_launch(void* const* d_in, const int* in_sizes, int n_in,
                              void* d_out, int out_size, void* d_ws, size_t ws_size,
                              hipStream_t stream) {
    const float* features = (const float*)d_in[0];
    const int*   src = (const int*)d_in[1];
    const int*   dst = (const int*)d_in[2];
    const float* W1  = (const float*)d_in[3];
    const float* al1 = (const float*)d_in[4];
    const float* ar1 = (const float*)d_in[5];
    const float* b1  = (const float*)d_in[6];
    const float* W2  = (const float*)d_in[7];
    const float* al2 = (const float*)d_in[8];
    const float* ar2 = (const float*)d_in[9];
    const float* b2  = (const float*)d_in[10];
    const float* W3  = (const float*)d_in[11];
    const float* al3 = (const float*)d_in[12];
    const float* ar3 = (const float*)d_in[13];
    const float* b3  = (const float*)d_in[14];

    const int N = in_sizes[0] / 128;   // 50000
    const int E = in_sizes[1];         // 800000
    const int NB = (N + 255) / 256;    // scan blocks

    float* ws   = (float*)d_ws;
    float* el   = ws;                        // [N,4]
    float* er   = el + (size_t)N * 4;        // [N,4]
    float* s    = er + (size_t)N * 4;        // [N,4]
    float* w    = s  + (size_t)N * 4;        // [E,4]
    int* cnt        = (int*)(w + (size_t)E * 4);   // [N]
    int* row_start  = cnt + N;                      // [N+1]
    int* cursor     = row_start + N + 1;            // [N]
    int* src_sorted = cursor + N;                   // [E]
    int* bsum       = src_sorted + E;               // [NB]
    int* boffs      = bsum + NB;                    // [NB]
    uintptr_t wp = (uintptr_t)(boffs + NB);
    wp = (wp + 15) & ~(uintptr_t)15;
    unsigned short* Wt    = (unsigned short*)wp;    // [256*256] bf16 max
    unsigned short* fconv = Wt + 256 * 256;         // [N,128] bf16 features
    unsigned short* featb = fconv + (size_t)N * 128;   // [N,256] GEMM out
    unsigned short* rstb  = featb + (size_t)N * 256;   // [N,256] agg out (layers 1-2)

    // ---- features -> bf16 once ----
    k_convert<<<(N * 128 / 4 + 255) / 256, 256, 0, stream>>>(features, fconv, N * 128 / 4);

    // ---- build dst-CSR (every call; deterministic, graph-capture safe) ----
    k_zero_int<<<(N + 255) / 256, 256, 0, stream>>>(cnt, N);
    k_hist<<<(E + 255) / 256, 256, 0, stream>>>(dst, cnt, E, N);
    k_bsum<<<NB, 256, 0, stream>>>(cnt, bsum, N);
    k_scan_bsum<<<1, 256, 0, stream>>>(bsum, boffs, row_start + N, NB);
    k_scan_write<<<NB, 256, 0, stream>>>(cnt, boffs, row_start, cursor, N);
    k_scatter<<<(E + 255) / 256, 256, 0, stream>>>(src, dst, cursor, src_sorted, E, N);

    // layer 1: A=fconv[N,128] -> featb[N,256] -> rstb[N,256] bf16 (+relu)
    run_layer(fconv, 128, W1, Wt, al1, ar1, b1, 4, featb, rstb, true,
              el, er, w, s, row_start, src_sorted, N, E, true, stream);
    // layer 2: A=rstb -> featb -> rstb (bf16, +relu; featb dead before rstb write)
    run_layer(rstb, 256, W2, Wt, al2, ar2, b2, 4, featb, rstb, true,
              el, er, w, s, row_start, src_sorted, N, E, true, stream);
    // layer 3: H=1; A=rstb -> featb[N,64] -> d_out fp32 (no relu; mean over 1 head = id)
    run_layer(rstb, 256, W3, Wt, al3, ar3, b3, 1, featb, d_out, false,
              el, er, w, s, row_start, src_sorted, N, E, false, stream);
}

// Round 14
// 554.747 us; speedup vs baseline: 2.6577x; 1.0578x over previous
//
#include <hip/hip_runtime.h>
#include <hip/hip_bf16.h>

#define LEAKY 0.2f

typedef __attribute__((ext_vector_type(8))) short short8;
typedef __attribute__((ext_vector_type(4))) float f32x4;

// round-to-nearest-even float -> bf16 bits (finite inputs)
__device__ inline unsigned short f2b(float f) {
    unsigned u = __float_as_uint(f);
    u += 0x7FFFu + ((u >> 16) & 1u);
    return (unsigned short)(u >> 16);
}
__device__ inline float b2f(unsigned short s) {
    return __uint_as_float(((unsigned)s) << 16);
}

// ---------------- misc ----------------

__global__ void k_zero_int(int* __restrict__ p, int n) {
    int i = blockIdx.x * blockDim.x + threadIdx.x;
    if (i < n) p[i] = 0;
}

// fp32 -> bf16 bulk convert (features), 4 elems/thread
__global__ void k_convert(const float* __restrict__ in, unsigned short* __restrict__ out, int n4) {
    int i = blockIdx.x * blockDim.x + threadIdx.x;
    if (i >= n4) return;
    float4 v = *(const float4*)(in + i * 4);
    ushort4 o;
    o.x = f2b(v.x); o.y = f2b(v.y); o.z = f2b(v.z); o.w = f2b(v.w);
    *(ushort4*)(out + i * 4) = o;
}

// all three weight transposes in one launch: Wt[m][k] = bf16(W[k][m])
__global__ void k_wt3(const float* __restrict__ W1, const float* __restrict__ W2,
                      const float* __restrict__ W3, unsigned short* __restrict__ Wt1,
                      unsigned short* __restrict__ Wt2, unsigned short* __restrict__ Wt3) {
    int idx = blockIdx.x * blockDim.x + threadIdx.x;
    if (idx < 32768) {                       // L1: K=128, M=256
        int m = idx >> 7, k = idx & 127;
        Wt1[idx] = f2b(W1[(size_t)k * 256 + m]);
    } else if (idx < 98304) {                // L2: K=256, M=256
        int j = idx - 32768;
        int m = j >> 8, k = j & 255;
        Wt2[j] = f2b(W2[(size_t)k * 256 + m]);
    } else if (idx < 114688) {               // L3: K=256, M=64
        int j = idx - 98304;
        int m = j >> 8, k = j & 255;
        Wt3[j] = f2b(W3[(size_t)k * 64 + m]);
    }
}

// ---------------- CSR build ----------------

__global__ void k_hist(const int* __restrict__ dst, int* __restrict__ cnt, int E, int N) {
    int e = blockIdx.x * blockDim.x + threadIdx.x;
    if (e >= E) return;
    int dn = dst[e];
    if ((unsigned)dn < (unsigned)N) atomicAdd(&cnt[dn], 1);
}

__global__ __launch_bounds__(256)
void k_bsum(const int* __restrict__ cnt, int* __restrict__ bsum, int N) {
    __shared__ int ws[4];
    int i = blockIdx.x * 256 + threadIdx.x;
    int lane = threadIdx.x & 63, wave = threadIdx.x >> 6;
    int v = (i < N) ? cnt[i] : 0;
    #pragma unroll
    for (int off = 32; off; off >>= 1) v += __shfl_down(v, off, 64);
    if (lane == 0) ws[wave] = v;
    __syncthreads();
    if (threadIdx.x == 0)
        bsum[blockIdx.x] = ws[0] + ws[1] + ws[2] + ws[3];
}

__global__ __launch_bounds__(256)
void k_scan_bsum(const int* __restrict__ bsum, int* __restrict__ boffs,
                 int* __restrict__ row_start_N, int NB) {
    __shared__ int ws[4];
    int tid = threadIdx.x, lane = tid & 63, wave = tid >> 6;
    int v = (tid < NB) ? bsum[tid] : 0;
    int x = v;
    #pragma unroll
    for (int off = 1; off < 64; off <<= 1) {
        int t = __shfl_up(x, off, 64);
        if (lane >= off) x += t;
    }
    if (lane == 63) ws[wave] = x;
    __syncthreads();
    if (tid == 0) {
        int c = 0;
        #pragma unroll
        for (int wv = 0; wv < 4; ++wv) { int t = ws[wv]; ws[wv] = c; c += t; }
    }
    __syncthreads();
    int excl = x - v + ws[wave];
    if (tid < NB) boffs[tid] = excl;
    if (tid == NB - 1) *row_start_N = excl + v;
}

__global__ __launch_bounds__(256)
void k_scan_write(const int* __restrict__ cnt, const int* __restrict__ boffs,
                  int* __restrict__ row_start, int* __restrict__ cursor, int N) {
    __shared__ int ws[4];
    int i = blockIdx.x * 256 + threadIdx.x;
    int tid = threadIdx.x, lane = tid & 63, wave = tid >> 6;
    int v = (i < N) ? cnt[i] : 0;
    int x = v;
    #pragma unroll
    for (int off = 1; off < 64; off <<= 1) {
        int t = __shfl_up(x, off, 64);
        if (lane >= off) x += t;
    }
    if (lane == 63) ws[wave] = x;
    __syncthreads();
    if (tid == 0) {
        int c = 0;
        #pragma unroll
        for (int wv = 0; wv < 4; ++wv) { int t = ws[wv]; ws[wv] = c; c += t; }
    }
    __syncthreads();
    int excl = x - v + ws[wave] + boffs[blockIdx.x];
    if (i < N) { row_start[i] = excl; cursor[i] = excl; }
}

__global__ void k_scatter(const int* __restrict__ src, const int* __restrict__ dst,
                          int* __restrict__ cursor, int* __restrict__ src_sorted,
                          int E, int N) {
    int e = blockIdx.x * blockDim.x + threadIdx.x;
    if (e >= E) return;
    int dn = dst[e];
    if ((unsigned)dn >= (unsigned)N) return;
    int pos = atomicAdd(&cursor[dn], 1);
    src_sorted[pos] = src[e];
}

// ---------------- MFMA GEMM (BN=128): Cb[N,M]=A[N,K]*W[K,M], all-bf16 flow ----

__global__ __launch_bounds__(256)
void k_gemm_mfma(const unsigned short* __restrict__ A, const unsigned short* __restrict__ Wt,
                 unsigned short* __restrict__ Cb, int N, int K, int M) {
    constexpr int STR = 40;
    __shared__ unsigned short As[128 * STR];
    __shared__ unsigned short Bs[128 * STR];
    const int tid  = threadIdx.x;
    const int wave = tid >> 6;
    const int lane = tid & 63;
    const int row0 = blockIdx.y * 128;
    const int col0 = blockIdx.x * 128;
    const int wr = (wave >> 1) * 64;
    const int wc = (wave & 1) * 64;
    const int m16 = lane & 15;
    const int q   = lane >> 4;

    const int s_row = tid >> 1;
    const int s_off = (tid & 1) * 16;

    f32x4 acc[4][4] = {};

    for (int k0 = 0; k0 < K; k0 += 32) {
        {
            int gr = row0 + s_row;
            short8 z = {};
            short8 v0 = z, v1 = z;
            if (gr < N) {
                const unsigned short* ap = A + (size_t)gr * K + k0 + s_off;
                v0 = *(const short8*)ap;
                v1 = *(const short8*)(ap + 8);
            }
            *(short8*)&As[s_row * STR + s_off]     = v0;
            *(short8*)&As[s_row * STR + s_off + 8] = v1;
        }
        {
            const unsigned short* sp = Wt + (size_t)(col0 + s_row) * K + k0 + s_off;
            *(short8*)&Bs[s_row * STR + s_off]     = *(const short8*)sp;
            *(short8*)&Bs[s_row * STR + s_off + 8] = *(const short8*)(sp + 8);
        }
        __syncthreads();

        short8 afr[4], bfr[4];
        #pragma unroll
        for (int rg = 0; rg < 4; ++rg)
            afr[rg] = *(const short8*)&As[(wr + rg * 16 + m16) * STR + q * 8];
        #pragma unroll
        for (int cg = 0; cg < 4; ++cg)
            bfr[cg] = *(const short8*)&Bs[(wc + cg * 16 + m16) * STR + q * 8];
        #pragma unroll
        for (int rg = 0; rg < 4; ++rg)
            #pragma unroll
            for (int cg = 0; cg < 4; ++cg)
                acc[rg][cg] = __builtin_amdgcn_mfma_f32_16x16x32_bf16(
                    afr[rg], bfr[cg], acc[rg][cg], 0, 0, 0);
        __syncthreads();
    }

    #pragma unroll
    for (int rg = 0; rg < 4; ++rg) {
        #pragma unroll
        for (int r = 0; r < 4; ++r) {
            int gr = row0 + wr + rg * 16 + q * 4 + r;
            if (gr < N) {
                unsigned short* bp = Cb + (size_t)gr * M + col0 + wc + m16;
                #pragma unroll
                for (int cg = 0; cg < 4; ++cg)
                    bp[cg * 16] = f2b(acc[rg][cg][r]);
            }
        }
    }
}

// ---------------- MFMA GEMM (M=64): 256x64 tile, 4 waves stacked ----

__global__ __launch_bounds__(256)
void k_gemm_mfma64(const unsigned short* __restrict__ A, const unsigned short* __restrict__ Wt,
                   unsigned short* __restrict__ Cb, int N, int K) {
    constexpr int M = 64;
    constexpr int STR = 40;
    __shared__ unsigned short As[256 * STR];
    __shared__ unsigned short Bs[64 * STR];
    const int tid  = threadIdx.x;
    const int wave = tid >> 6;
    const int lane = tid & 63;
    const int row0 = blockIdx.x * 256;
    const int wr = wave * 64;
    const int m16 = lane & 15;
    const int q   = lane >> 4;

    const int s_row = tid >> 1;
    const int s_off = (tid & 1) * 16;
    const int b_row = tid >> 2;
    const int b_chk = (tid & 3) * 8;

    f32x4 acc[4][4] = {};

    for (int k0 = 0; k0 < K; k0 += 32) {
        #pragma unroll
        for (int p = 0; p < 2; ++p) {
            int r = s_row + p * 128;
            int gr = row0 + r;
            short8 z = {};
            short8 v0 = z, v1 = z;
            if (gr < N) {
                const unsigned short* ap = A + (size_t)gr * K + k0 + s_off;
                v0 = *(const short8*)ap;
                v1 = *(const short8*)(ap + 8);
            }
            *(short8*)&As[r * STR + s_off]     = v0;
            *(short8*)&As[r * STR + s_off + 8] = v1;
        }
        {
            const unsigned short* sp = Wt + (size_t)b_row * K + k0 + b_chk;
            *(short8*)&Bs[b_row * STR + b_chk] = *(const short8*)sp;
        }
        __syncthreads();

        short8 afr[4], bfr[4];
        #pragma unroll
        for (int rg = 0; rg < 4; ++rg)
            afr[rg] = *(const short8*)&As[(wr + rg * 16 + m16) * STR + q * 8];
        #pragma unroll
        for (int cg = 0; cg < 4; ++cg)
            bfr[cg] = *(const short8*)&Bs[(cg * 16 + m16) * STR + q * 8];
        #pragma unroll
        for (int rg = 0; rg < 4; ++rg)
            #pragma unroll
            for (int cg = 0; cg < 4; ++cg)
                acc[rg][cg] = __builtin_amdgcn_mfma_f32_16x16x32_bf16(
                    afr[rg], bfr[cg], acc[rg][cg], 0, 0, 0);
        __syncthreads();
    }

    #pragma unroll
    for (int rg = 0; rg < 4; ++rg) {
        #pragma unroll
        for (int r = 0; r < 4; ++r) {
            int gr = row0 + wr + rg * 16 + q * 4 + r;
            if (gr < N) {
                unsigned short* bp = Cb + (size_t)gr * M + m16;
                #pragma unroll
                for (int cg = 0; cg < 4; ++cg)
                    bp[cg * 16] = f2b(acc[rg][cg][r]);
            }
        }
    }
}

// ---------------- attention pieces (CSR, atomic-free) ----------------

// one wave per (node,head), bf16 feat read
__global__ __launch_bounds__(256)
void k_el_er(const unsigned short* __restrict__ featb, const float* __restrict__ al,
             const float* __restrict__ ar, float* __restrict__ el,
             float* __restrict__ er, int NH, int H) {
    int g = blockIdx.x * 4 + (threadIdx.x >> 6);
    int lane = threadIdx.x & 63;
    if (g >= NH) return;
    int h = g % H;
    float v  = b2f(featb[(size_t)g * 64 + lane]);
    float sl = v * al[h * 64 + lane];
    float sr = v * ar[h * 64 + lane];
    #pragma unroll
    for (int off = 32; off; off >>= 1) {
        sl += __shfl_down(sl, off, 64);
        sr += __shfl_down(sr, off, 64);
    }
    if (lane == 0) { el[g] = sl; er[g] = sr; }
}

// softmax per node: ONE WAVE per node. lane -> (edge-offset eo, head h);
// gathers run parallel across 64/H lanes (quad-coalesced el reads for H=4,
// fully-coalesced w writes); max/sum via xor-butterfly over same-h lanes.
// w gets unnormalized exp; s = 1/sum (applied in agg epilogue).
template<int H>
__global__ __launch_bounds__(256)
void k_node_msw(const int* __restrict__ row_start, const int* __restrict__ src_sorted,
                const float* __restrict__ el, const float* __restrict__ er,
                float* __restrict__ w, float* __restrict__ s, int N) {
    constexpr int STRIDE = 64 / H;
    const int n = blockIdx.x * 4 + (threadIdx.x >> 6);
    if (n >= N) return;
    const int lane = threadIdx.x & 63;
    const int eo = lane / H;
    const int h  = lane % H;
    float erv = er[n * H + h];
    int b0 = row_start[n], b1 = row_start[n + 1];
    float mx = -INFINITY;
    for (int i = b0 + eo; i < b1; i += STRIDE) {
        float x = el[src_sorted[i] * H + h] + erv;
        x = (x > 0.f) ? x : LEAKY * x;
        w[(size_t)i * H + h] = x;
        mx = fmaxf(mx, x);
    }
    #pragma unroll
    for (int off = H; off < 64; off <<= 1)
        mx = fmaxf(mx, __shfl_xor(mx, off, 64));
    float sum = 0.f;
    for (int i = b0 + eo; i < b1; i += STRIDE) {
        float e = __expf(w[(size_t)i * H + h] - mx);
        sum += e;
        w[(size_t)i * H + h] = e;
    }
    #pragma unroll
    for (int off = H; off < 64; off <<= 1)
        sum += __shfl_xor(sum, off, 64);
    if (lane < H) s[n * H + lane] = 1.0f / fmaxf(sum, 1e-30f);
}

// Aggregation, packed bf16 octets (uint4 = 8 bf16 per edge per thread).
// P = M/8 threads per node; unnormalized weights, 1/sum + bias in epilogue.
template<int OUTBF>
__global__ __launch_bounds__(256)
void k_agg_b(const int* __restrict__ row_start, const int* __restrict__ src_sorted,
             const uint4* __restrict__ featp, const float* __restrict__ w,
             const float* __restrict__ s, const float* __restrict__ bias,
             void* __restrict__ outv, int H, int N, int do_relu) {
    const int M = H * 64;
    const int P = M >> 3;
    const int G = 256 / P;
    const int grp = threadIdx.x / P;
    const int t = threadIdx.x - grp * P;
    const int n = blockIdx.x * G + grp;
    if (n >= N) return;
    const int d0 = t * 8;
    const int h = d0 >> 6;

    float a[8] = {};
    int b0 = row_start[n], b1 = row_start[n + 1];
    int i = b0;
    for (; i + 4 <= b1; i += 4) {
        int ss[4]; float wv[4]; uint4 pv[4];
        #pragma unroll
        for (int j = 0; j < 4; ++j) ss[j] = src_sorted[i + j];
        #pragma unroll
        for (int j = 0; j < 4; ++j) wv[j] = w[(size_t)(i + j) * H + h];
        #pragma unroll
        for (int j = 0; j < 4; ++j) pv[j] = featp[(size_t)ss[j] * P + t];
        #pragma unroll
        for (int j = 0; j < 4; ++j) {
            a[0] = fmaf(__uint_as_float(pv[j].x << 16),         wv[j], a[0]);
            a[1] = fmaf(__uint_as_float(pv[j].x & 0xFFFF0000u), wv[j], a[1]);
            a[2] = fmaf(__uint_as_float(pv[j].y << 16),         wv[j], a[2]);
            a[3] = fmaf(__uint_as_float(pv[j].y & 0xFFFF0000u), wv[j], a[3]);
            a[4] = fmaf(__uint_as_float(pv[j].z << 16),         wv[j], a[4]);
            a[5] = fmaf(__uint_as_float(pv[j].z & 0xFFFF0000u), wv[j], a[5]);
            a[6] = fmaf(__uint_as_float(pv[j].w << 16),         wv[j], a[6]);
            a[7] = fmaf(__uint_as_float(pv[j].w & 0xFFFF0000u), wv[j], a[7]);
        }
    }
    for (; i < b1; ++i) {
        uint4 pv = featp[(size_t)src_sorted[i] * P + t];
        float wv = w[(size_t)i * H + h];
        a[0] = fmaf(__uint_as_float(pv.x << 16),         wv, a[0]);
        a[1] = fmaf(__uint_as_float(pv.x & 0xFFFF0000u), wv, a[1]);
        a[2] = fmaf(__uint_as_float(pv.y << 16),         wv, a[2]);
        a[3] = fmaf(__uint_as_float(pv.y & 0xFFFF0000u), wv, a[3]);
        a[4] = fmaf(__uint_as_float(pv.z << 16),         wv, a[4]);
        a[5] = fmaf(__uint_as_float(pv.z & 0xFFFF0000u), wv, a[5]);
        a[6] = fmaf(__uint_as_float(pv.w << 16),         wv, a[6]);
        a[7] = fmaf(__uint_as_float(pv.w & 0xFFFF0000u), wv, a[7]);
    }
    float rs = s[n * H + h];
    float4 bv0 = *(const float4*)(bias + d0);
    float4 bv1 = *(const float4*)(bias + d0 + 4);
    a[0] = fmaf(a[0], rs, bv0.x); a[1] = fmaf(a[1], rs, bv0.y);
    a[2] = fmaf(a[2], rs, bv0.z); a[3] = fmaf(a[3], rs, bv0.w);
    a[4] = fmaf(a[4], rs, bv1.x); a[5] = fmaf(a[5], rs, bv1.y);
    a[6] = fmaf(a[6], rs, bv1.z); a[7] = fmaf(a[7], rs, bv1.w);
    if (do_relu) {
        #pragma unroll
        for (int j = 0; j < 8; ++j) a[j] = fmaxf(a[j], 0.f);
    }
    if (OUTBF) {
        uint4 o;
        o.x = (unsigned)f2b(a[0]) | ((unsigned)f2b(a[1]) << 16);
        o.y = (unsigned)f2b(a[2]) | ((unsigned)f2b(a[3]) << 16);
        o.z = (unsigned)f2b(a[4]) | ((unsigned)f2b(a[5]) << 16);
        o.w = (unsigned)f2b(a[6]) | ((unsigned)f2b(a[7]) << 16);
        *(uint4*)((unsigned short*)outv + (size_t)n * M + d0) = o;
    } else {
        *(float4*)((float*)outv + (size_t)n * M + d0)     = make_float4(a[0], a[1], a[2], a[3]);
        *(float4*)((float*)outv + (size_t)n * M + d0 + 4) = make_float4(a[4], a[5], a[6], a[7]);
    }
}

// ---------------- host side ----------------

static void run_layer(const unsigned short* A, int K, const unsigned short* Wt,
                      const float* al_, const float* ar_, const float* b_, int H,
                      unsigned short* featb, void* rstOut, bool outBf,
                      float* el, float* er, float* w, float* s,
                      const int* row_start, const int* src_sorted,
                      int N, int E, bool do_relu, hipStream_t stream) {
    const int M = H * 64;
    if (M % 128 == 0) {
        dim3 gg(M / 128, (N + 127) / 128);
        k_gemm_mfma<<<gg, 256, 0, stream>>>(A, Wt, featb, N, K, M);
    } else {
        k_gemm_mfma64<<<(N + 255) / 256, 256, 0, stream>>>(A, Wt, featb, N, K);
    }

    int nh = N * H;
    k_el_er<<<(nh + 3) / 4, 256, 0, stream>>>(featb, al_, ar_, el, er, nh, H);
    if (H == 4)
        k_node_msw<4><<<(N + 3) / 4, 256, 0, stream>>>(row_start, src_sorted, el, er, w, s, N);
    else
        k_node_msw<1><<<(N + 3) / 4, 256, 0, stream>>>(row_start, src_sorted, el, er, w, s, N);

    int G = 256 / (M / 8);
    if (outBf)
        k_agg_b<1><<<(N + G - 1) / G, 256, 0, stream>>>(row_start, src_sorted,
                                                        (const uint4*)featb, w, s,
                                                        b_, rstOut, H, N, do_relu ? 1 : 0);
    else
        k_agg_b<0><<<(N + G - 1) / G, 256, 0, stream>>>(row_start, src_sorted,
                                                        (const uint4*)featb, w, s,
                                                        b_, rstOut, H, N, do_relu ? 1 : 0);
}

extern "C" void kernel_launch(void* const* d_in, const int* in_sizes, int n_in,
                              void* d_out, int out_size, void* d_ws, size_t ws_size,
                              hipStream_t stream) {
    const float* features = (const float*)d_in[0];
    const int*   src = (const int*)d_in[1];
    const int*   dst = (const int*)d_in[2];
    const float* W1  = (const float*)d_in[3];
    const float* al1 = (const float*)d_in[4];
    const float* ar1 = (const float*)d_in[5];
    const float* b1  = (const float*)d_in[6];
    const float* W2  = (const float*)d_in[7];
    const float* al2 = (const float*)d_in[8];
    const float* ar2 = (const float*)d_in[9];
    const float* b2  = (const float*)d_in[10];
    const float* W3  = (const float*)d_in[11];
    const float* al3 = (const float*)d_in[12];
    const float* ar3 = (const float*)d_in[13];
    const float* b3  = (const float*)d_in[14];

    const int N = in_sizes[0] / 128;   // 50000
    const int E = in_sizes[1];         // 800000
    const int NB = (N + 255) / 256;    // scan blocks

    float* ws   = (float*)d_ws;
    float* el   = ws;                        // [N,4]
    float* er   = el + (size_t)N * 4;        // [N,4]
    float* s    = er + (size_t)N * 4;        // [N,4]
    float* w    = s  + (size_t)N * 4;        // [E,4]
    int* cnt        = (int*)(w + (size_t)E * 4);   // [N]
    int* row_start  = cnt + N;                      // [N+1]
    int* cursor     = row_start + N + 1;            // [N]
    int* src_sorted = cursor + N;                   // [E]
    int* bsum       = src_sorted + E;               // [NB]
    int* boffs      = bsum + NB;                    // [NB]
    uintptr_t wp = (uintptr_t)(boffs + NB);
    wp = (wp + 15) & ~(uintptr_t)15;
    unsigned short* Wt1   = (unsigned short*)wp;       // [256*128]
    unsigned short* Wt2   = Wt1 + 32768;               // [256*256]
    unsigned short* Wt3   = Wt2 + 65536;               // [64*256]
    unsigned short* fconv = Wt3 + 16384;               // [N,128] bf16 features
    unsigned short* featb = fconv + (size_t)N * 128;   // [N,256] GEMM out
    unsigned short* rstb  = featb + (size_t)N * 256;   // [N,256] agg out (layers 1-2)

    // ---- input conversions (independent of CSR) ----
    k_convert<<<(N * 128 / 4 + 255) / 256, 256, 0, stream>>>(features, fconv, N * 128 / 4);
    k_wt3<<<(114688 + 255) / 256, 256, 0, stream>>>(W1, W2, W3, Wt1, Wt2, Wt3);

    // ---- build dst-CSR (every call; deterministic, graph-capture safe) ----
    k_zero_int<<<(N + 255) / 256, 256, 0, stream>>>(cnt, N);
    k_hist<<<(E + 255) / 256, 256, 0, stream>>>(dst, cnt, E, N);
    k_bsum<<<NB, 256, 0, stream>>>(cnt, bsum, N);
    k_scan_bsum<<<1, 256, 0, stream>>>(bsum, boffs, row_start + N, NB);
    k_scan_write<<<NB, 256, 0, stream>>>(cnt, boffs, row_start, cursor, N);
    k_scatter<<<(E + 255) / 256, 256, 0, stream>>>(src, dst, cursor, src_sorted, E, N);

    // layer 1: A=fconv[N,128] -> featb[N,256] -> rstb[N,256] bf16 (+relu)
    run_layer(fconv, 128, Wt1, al1, ar1, b1, 4, featb, rstb, true,
              el, er, w, s, row_start, src_sorted, N, E, true, stream);
    // layer 2: A=rstb -> featb -> rstb (bf16, +relu)
    run_layer(rstb, 256, Wt2, al2, ar2, b2, 4, featb, rstb, true,
              el, er, w, s, row_start, src_sorted, N, E, true, stream);
    // layer 3: H=1; A=rstb -> featb[N,64] -> d_out fp32 (no relu; mean over 1 head = id)
    run_layer(rstb, 256, Wt3, al3, ar3, b3, 1, featb, d_out, false,
              el, er, w, s, row_start, src_sorted, N, E, false, stream);
}